// Round 13
// baseline (162.322 us; speedup 1.0000x reference)
//
#include <hip/hip_runtime.h>

// GAT layer fused, MI355X gfx950 — v12: column-split-pair flash. 8 waves =
// 4 row-groups (32 rows) x 2 col-halves (128 cols). K-frags read once per
// wave feed 2 row-subtiles; V-frags halved per wave -> LDS bytes/row cut
// 2.7x vs v11. Swapped QK^T, register P (v11-verified layout), packed
// 16-bit adj masks. Pipeline: memset -> prep_k -> hnew_k -> attn_k -> comb_k.

typedef __attribute__((ext_vector_type(8))) short short8;   // 8 x bf16 (4 VGPR)
typedef __attribute__((ext_vector_type(4))) float f32x4;    // MFMA C/D frag

#define NN 8192
#define DD 256
#define NEGB -1.2983e16f  // -9e15 * log2(e): NEG_BIG in base-2 softmax domain

__device__ __forceinline__ unsigned short f2bf(float f) {
  unsigned u = __builtin_bit_cast(unsigned, f);
  u += 0x7FFFu + ((u >> 16) & 1u);  // RNE
  return (unsigned short)(u >> 16);
}
__device__ __forceinline__ float bf2f(unsigned short s) {
  unsigned u = ((unsigned)s) << 16;
  return __builtin_bit_cast(float, u);
}
__device__ __forceinline__ f32x4 mfma16(short8 a, short8 b, f32x4 c) {
  return __builtin_amdgcn_mfma_f32_16x16x32_bf16(a, b, c, 0, 0, 0);
}
// async global->LDS, 16B per lane; lds ptr wave-uniform base
__device__ __forceinline__ void gld16(const unsigned short* g, unsigned short* l) {
  __builtin_amdgcn_global_load_lds(
      (const __attribute__((address_space(1))) void*)g,
      (__attribute__((address_space(3))) void*)l, 16, 0, 0);
}
// load 16 adj values for (2 row-subtiles x 2 key-halves x 4 keys), pack to bits
// bit index = (rt*2 + nt)*4 + q
__device__ __forceinline__ unsigned ldmask(const int* __restrict__ adj, size_t a0,
                                           size_t a1, int joff, int lg) {
  int4 a = *(const int4*)(adj + a0 + joff + lg * 4);
  int4 b = *(const int4*)(adj + a0 + joff + 16 + lg * 4);
  int4 c = *(const int4*)(adj + a1 + joff + lg * 4);
  int4 d = *(const int4*)(adj + a1 + joff + 16 + lg * 4);
  unsigned m = 0;
  m |= (a.x != 0) << 0;  m |= (a.y != 0) << 1;
  m |= (a.z != 0) << 2;  m |= (a.w != 0) << 3;
  m |= (b.x != 0) << 4;  m |= (b.y != 0) << 5;
  m |= (b.z != 0) << 6;  m |= (b.w != 0) << 7;
  m |= (c.x != 0) << 8;  m |= (c.y != 0) << 9;
  m |= (c.z != 0) << 10; m |= (c.w != 0) << 11;
  m |= (d.x != 0) << 12; m |= (d.y != 0) << 13;
  m |= (d.z != 0) << 14; m |= (d.w != 0) << 15;
  return m;
}

// ---- prep: count_k (blocks 0..31) | pack_wf (blocks 32..63) ---------------
__global__ __launch_bounds__(256) void prep_k(const float* __restrict__ W,
                                              const int* __restrict__ adj,
                                              unsigned short* __restrict__ Wf,
                                              int* __restrict__ kout) {
  const int bx = blockIdx.x, tid = threadIdx.x;
  if (bx < 32) {  // k = sum(adj[:,0] != 0)
    __shared__ int red[256];
    int gid = bx * 256 + tid;
    red[tid] = (adj[(size_t)gid * NN] != 0);
    __syncthreads();
    for (int off = 128; off; off >>= 1) {
      if (tid < off) red[tid] += red[tid + off];
      __syncthreads();
    }
    if (tid == 0) atomicAdd(kout, red[0]);
  } else {  // W -> bf16 B-frags
    int gid = (bx - 32) * 256 + tid;
    int l = gid & 63, f = gid >> 6, n16 = f >> 3, kk = f & 7;
    int lr = l & 15, lg = l >> 4;
    const float* src = W + (size_t)(n16 * 16 + lr) * DD + kk * 32 + lg * 8;
    float4 w0 = *(const float4*)src, w1 = *(const float4*)(src + 4);
    short8 o;
    o[0] = (short)f2bf(w0.x); o[1] = (short)f2bf(w0.y);
    o[2] = (short)f2bf(w0.z); o[3] = (short)f2bf(w0.w);
    o[4] = (short)f2bf(w1.x); o[5] = (short)f2bf(w1.y);
    o[6] = (short)f2bf(w1.z); o[7] = (short)f2bf(w1.w);
    *(short8*)(Wf + (size_t)gid * 8) = o;
  }
}

// ---- fused conv + h_new: h(f32) -> A-frags (regs) -> hQf store + GEMM -----
// hnV stored with k-permutation matching swapped-QK P register order.
__global__ __launch_bounds__(256) void hnew_k(const float* __restrict__ h,
                                              const unsigned short* __restrict__ Wf,
                                              const float* __restrict__ bias,
                                              unsigned short* __restrict__ hQf,
                                              unsigned short* __restrict__ hnb,
                                              unsigned short* __restrict__ hnV) {
  const int tid = threadIdx.x, w = tid >> 6, l = tid & 63, lr = l & 15, lg = l >> 4;
  const int row0 = blockIdx.x * 64 + w * 16;
  const int j16 = row0 >> 4;

  short8 a[8];
#pragma unroll
  for (int kk = 0; kk < 8; ++kk) {  // convert own rows f32 -> bf16 frags
    const float* src = h + (size_t)(row0 + lr) * DD + kk * 32 + lg * 8;
    float4 v0 = *(const float4*)src, v1 = *(const float4*)(src + 4);
    short8 o;
    o[0] = (short)f2bf(v0.x); o[1] = (short)f2bf(v0.y);
    o[2] = (short)f2bf(v0.z); o[3] = (short)f2bf(v0.w);
    o[4] = (short)f2bf(v1.x); o[5] = (short)f2bf(v1.y);
    o[6] = (short)f2bf(v1.z); o[7] = (short)f2bf(v1.w);
    a[kk] = o;
    *(short8*)(hQf + ((size_t)(j16 * 8 + kk) * 64 + l) * 8) = o;  // K/Q frags
  }

  f32x4 acc[16];
#pragma unroll
  for (int nt = 0; nt < 16; ++nt) acc[nt] = (f32x4){0.f, 0.f, 0.f, 0.f};
#pragma unroll
  for (int kk = 0; kk < 8; ++kk)
#pragma unroll
    for (int nt = 0; nt < 16; ++nt) {
      short8 bf = *(const short8*)(Wf + ((size_t)(nt * 8 + kk) * 64 + l) * 8);
      acc[nt] = mfma16(a[kk], bf, acc[nt]);
    }
  const int rowbase = row0 + lg * 4;                // 4 rows, q contiguous
  const int eb = ((rowbase >> 4) & 1) * 4;          // permuted elem base
#pragma unroll
  for (int nt = 0; nt < 16; ++nt) {
    const int col = nt * 16 + lr;
    const float bv = bias[col];
    unsigned short r16[4];
#pragma unroll
    for (int q = 0; q < 4; ++q) r16[q] = f2bf(acc[nt][q] + bv);
#pragma unroll
    for (int q = 0; q < 4; ++q) hnb[(size_t)(rowbase + q) * DD + col] = r16[q];
    ushort4 o4 = {r16[0], r16[1], r16[2], r16[3]};
    *(ushort4*)(hnV + (((size_t)(rowbase >> 5) * 16 + nt) * 64 + lg * 16 + lr) * 8 +
                eb) = o4;
  }
}

// ---- flash attention partials: column-split pairs -------------------------
// Grid (S=16 chunks, 64 tiles of 128 rows). 8 waves: g = w>>1 row-group (32
// rows), hc = w&1 col-half (128 cols). Per iter/wave: 16 K-frag reads feed
// both row-subtiles (32 QK MFMA), 8 V-frag reads feed both (16 PV MFMA).
__global__ __launch_bounds__(512, 1) void attn_k(
    const unsigned short* __restrict__ hQf, const unsigned short* __restrict__ hnV,
    const int* __restrict__ adj, const int* __restrict__ kptr,
    float* __restrict__ pl, unsigned short* __restrict__ pO, int T) {
  __shared__ __align__(16) unsigned short sK[2][8192];  // 16KB x2
  __shared__ __align__(16) unsigned short sV[2][8192];  // 16KB x2

  const int tid = threadIdx.x, w = tid >> 6, l = tid & 63, lr = l & 15, lg = l >> 4;
  const int c = blockIdx.x, ty = blockIdx.y;
  const int i0 = ty * 128;
  const int kid = *kptr;
  if (i0 + 128 <= kid) return;  // whole tile identity: comb_k handles it

  const int g = w >> 1, hc = w & 1;
  const int r0 = i0 + g * 32;  // this wave's 32 rows (2 subtiles of 16)

  short8 qf[2][8];  // Q frags (B operand), 2 row-subtiles
#pragma unroll
  for (int rt = 0; rt < 2; ++rt)
#pragma unroll
    for (int kk = 0; kk < 8; ++kk)
      qf[rt][kk] =
          *(const short8*)(hQf + ((size_t)(((r0 >> 4) + rt) * 8 + kk) * 64 + l) * 8);

  f32x4 Oacc[2][8];  // [row-subtile][col-frag within this wave's half]
#pragma unroll
  for (int rt = 0; rt < 2; ++rt)
#pragma unroll
    for (int cn = 0; cn < 8; ++cn) Oacc[rt][cn] = (f32x4){0.f, 0.f, 0.f, 0.f};
  float lsum[2] = {0.f, 0.f};
  const float c1 = 0.09016844005556021f;  // log2(e)/sqrt(256)

  const size_t arow0 = (size_t)(r0 + lr) * NN;       // subtile-0 mask row
  const size_t arow1 = (size_t)(r0 + 16 + lr) * NN;  // subtile-1 mask row

  const int jt0 = c * T;

  // ---- prologue: stage tile jt0 into buf 0 (each wave: 2 segs per buffer) --
  {
    const unsigned short* srcK = hQf + (size_t)jt0 * 8192;
    const unsigned short* srcV = hnV + (size_t)jt0 * 8192;
#pragma unroll
    for (int s = 0; s < 2; ++s) {
      const int so = (w * 2 + s) * 512;
      gld16(srcK + so + l * 8, &sK[0][so]);
      gld16(srcV + so + l * 8, &sV[0][so]);
    }
  }
  unsigned mc = ldmask(adj, arow0, arow1, jt0 * 32, lg), mn = 0;
  __syncthreads();

  for (int t = 0; t < T; ++t) {
    const int cur = t & 1;
    if (t + 1 < T) {  // stage next tile + next packed mask
      const int jn = jt0 + t + 1;
      const unsigned short* srcK = hQf + (size_t)jn * 8192;
      const unsigned short* srcV = hnV + (size_t)jn * 8192;
#pragma unroll
      for (int s = 0; s < 2; ++s) {
        const int so = (w * 2 + s) * 512;
        gld16(srcK + so + l * 8, &sK[cur ^ 1][so]);
        gld16(srcV + so + l * 8, &sV[cur ^ 1][so]);
      }
      mn = ldmask(adj, arow0, arow1, jn * 32, lg);
    }

    // ---- S^T = K . Q^T (K=256): 16 K-frag reads -> 32 MFMAs (2x reuse) ----
    f32x4 S2[2][2];
#pragma unroll
    for (int rt = 0; rt < 2; ++rt)
#pragma unroll
      for (int nt = 0; nt < 2; ++nt) S2[rt][nt] = (f32x4){0.f, 0.f, 0.f, 0.f};
    __builtin_amdgcn_s_setprio(1);
#pragma unroll
    for (int kk = 0; kk < 8; ++kk)
#pragma unroll
      for (int nt = 0; nt < 2; ++nt) {
        short8 kf = *(const short8*)(&sK[cur][(nt * 8 + kk) * 512 + l * 8]);
        S2[0][nt] = mfma16(kf, qf[0][kk], S2[0][nt]);
        S2[1][nt] = mfma16(kf, qf[1][kk], S2[1][nt]);
      }
    __builtin_amdgcn_s_setprio(0);

    // ---- masked softmax numerators (pure sums), register P per subtile ----
    short8 pa[2];
#pragma unroll
    for (int rt = 0; rt < 2; ++rt) {
      float p[2][4];
#pragma unroll
      for (int nt = 0; nt < 2; ++nt)
#pragma unroll
        for (int q = 0; q < 4; ++q) {
          float sv = ((mc >> ((rt * 2 + nt) * 4 + q)) & 1u)
                         ? fminf(S2[rt][nt][q] * c1, 60.f)
                         : NEGB;
          p[nt][q] = __builtin_amdgcn_exp2f(sv);
        }
      lsum[rt] += ((p[0][0] + p[0][1]) + (p[0][2] + p[0][3])) +
                  ((p[1][0] + p[1][1]) + (p[1][2] + p[1][3]));
#pragma unroll
      for (int e = 0; e < 4; ++e) {
        pa[rt][e] = (short)f2bf(p[0][e]);
        pa[rt][e + 4] = (short)f2bf(p[1][e]);
      }
    }

    // ---- PV: 8 V-frag reads (this col-half) -> 16 MFMAs (2x reuse) ----
    __builtin_amdgcn_s_setprio(1);
#pragma unroll
    for (int cn = 0; cn < 8; ++cn) {
      short8 vf = *(const short8*)(&sV[cur][(hc * 8 + cn) * 512 + l * 8]);
      Oacc[0][cn] = mfma16(pa[0], vf, Oacc[0][cn]);
      Oacc[1][cn] = mfma16(pa[1], vf, Oacc[1][cn]);
    }
    __builtin_amdgcn_s_setprio(0);

    mc = mn;
    __syncthreads();  // staged tile complete + buffers safe to overwrite
  }

  // ---- reduce denominators across lg (shfl 16,32), write partials ----
#pragma unroll
  for (int rt = 0; rt < 2; ++rt) {
    float s = lsum[rt];
    s += __shfl_xor(s, 16);
    s += __shfl_xor(s, 32);
    if (hc == 0 && lg == 0) pl[(size_t)c * NN + r0 + rt * 16 + lr] = s;
  }
#pragma unroll
  for (int rt = 0; rt < 2; ++rt)
#pragma unroll
    for (int cn = 0; cn < 8; ++cn)
#pragma unroll
      for (int q = 0; q < 4; ++q) {
        int row = r0 + rt * 16 + lg * 4 + q;
        int col = hc * 128 + cn * 16 + lr;
        pO[((size_t)c * NN + row) * DD + col] = f2bf(Oacc[rt][cn][q]);
      }
}

// ---- combine chunks + epilogue: 4 rows/block, ushort4 lanes ---------------
__global__ __launch_bounds__(256) void comb_k(const float* __restrict__ pl,
                                              const unsigned short* __restrict__ pO,
                                              const unsigned short* __restrict__ hnb,
                                              const int* __restrict__ kptr,
                                              float* __restrict__ out, int S) {
  const int row = blockIdx.x * 4 + (threadIdx.x >> 6);
  const int col = (threadIdx.x & 63) * 4;
  const int kid = *kptr;
  ushort4 hv = *(const ushort4*)(hnb + (size_t)row * DD + col);
  float v0 = bf2f(hv.x), v1 = bf2f(hv.y), v2 = bf2f(hv.z), v3 = bf2f(hv.w);
  float4 r;
  if (row < kid) {
    r.x = v0; r.y = v1; r.z = v2; r.w = v3;
  } else {
    float L = 0.f, a0 = 0.f, a1 = 0.f, a2 = 0.f, a3 = 0.f;
    for (int cc = 0; cc < S; ++cc) {
      L += pl[(size_t)cc * NN + row];
      ushort4 ov = *(const ushort4*)(pO + ((size_t)cc * NN + row) * DD + col);
      a0 += bf2f(ov.x); a1 += bf2f(ov.y); a2 += bf2f(ov.z); a3 += bf2f(ov.w);
    }
    float inv = 0.5f / L;
    r.x = a0 * inv + 0.5f * v0; r.y = a1 * inv + 0.5f * v1;
    r.z = a2 * inv + 0.5f * v2; r.w = a3 * inv + 0.5f * v3;
  }
  r.x = fmaxf(r.x, 0.f); r.y = fmaxf(r.y, 0.f);
  r.z = fmaxf(r.z, 0.f); r.w = fmaxf(r.w, 0.f);
  *(float4*)(out + (size_t)row * DD + col) = r;
}

extern "C" void kernel_launch(void* const* d_in, const int* in_sizes, int n_in,
                              void* d_out, int out_size, void* d_ws, size_t ws_size,
                              hipStream_t stream) {
  const float* h = (const float*)d_in[0];
  const int* adj = (const int*)d_in[1];
  const float* W = (const float*)d_in[2];
  const float* b = (const float*)d_in[3];
  float* out = (float*)d_out;

  char* ws = (char*)d_ws;
  const size_t MB4 = (size_t)NN * DD * 2;  // 4 MiB
  int* kbuf = (int*)ws;
  unsigned short* hQf = (unsigned short*)(ws + 256);
  unsigned short* hnb = (unsigned short*)(ws + 256 + MB4);
  unsigned short* hnV = (unsigned short*)(ws + 256 + 2 * MB4);
  unsigned short* Wf = (unsigned short*)(ws + 256 + 3 * MB4);  // 128 KiB
  char* dyn = ws + 256 + 3 * MB4 + (256 << 10);

  size_t fixed = 256 + 3 * MB4 + (256 << 10);
  int S = 16;
  while (S > 1 && fixed + (size_t)S * NN * (DD * 2 + 4) > ws_size) S >>= 1;
  const int T = 256 / S;

  float* pl = (float*)dyn;
  unsigned short* pO = (unsigned short*)(pl + (size_t)S * NN);

  hipMemsetAsync(kbuf, 0, 4, stream);
  hipLaunchKernelGGL(prep_k, dim3(64), dim3(256), 0, stream, W, adj, Wf, kbuf);
  hipLaunchKernelGGL(hnew_k, dim3(NN / 64), dim3(256), 0, stream,
                     h, Wf, b, hQf, hnb, hnV);
  hipLaunchKernelGGL(attn_k, dim3(S, NN / 128), dim3(512), 0, stream,
                     hQf, hnV, adj, kbuf, pl, pO, T);
  hipLaunchKernelGGL(comb_k, dim3(NN / 4), dim3(256), 0, stream, pl, pO, hnb, kbuf, out, S);
}

// Round 14
// 138.609 us; speedup vs baseline: 1.1711x; 1.1711x over previous
//
#include <hip/hip_runtime.h>

// GAT layer fused, MI355X gfx950 — v13: v12's column-split math in v11's
// proven 4-wave 256-thread block shape. Wave = (row-group of 32, col-half of
// 128): 24 LDS frag reads/iter serve 32 rows (1.5KB/row, -25% vs v11).
// Swapped QK^T, register P, packed masks. memset->prep->hnew->attn->comb.

typedef __attribute__((ext_vector_type(8))) short short8;   // 8 x bf16 (4 VGPR)
typedef __attribute__((ext_vector_type(4))) float f32x4;    // MFMA C/D frag

#define NN 8192
#define DD 256
#define NEGB -1.2983e16f  // -9e15 * log2(e): NEG_BIG in base-2 softmax domain

__device__ __forceinline__ unsigned short f2bf(float f) {
  unsigned u = __builtin_bit_cast(unsigned, f);
  u += 0x7FFFu + ((u >> 16) & 1u);  // RNE
  return (unsigned short)(u >> 16);
}
__device__ __forceinline__ float bf2f(unsigned short s) {
  unsigned u = ((unsigned)s) << 16;
  return __builtin_bit_cast(float, u);
}
__device__ __forceinline__ f32x4 mfma16(short8 a, short8 b, f32x4 c) {
  return __builtin_amdgcn_mfma_f32_16x16x32_bf16(a, b, c, 0, 0, 0);
}
// async global->LDS, 16B per lane; lds ptr wave-uniform base
__device__ __forceinline__ void gld16(const unsigned short* g, unsigned short* l) {
  __builtin_amdgcn_global_load_lds(
      (const __attribute__((address_space(1))) void*)g,
      (__attribute__((address_space(3))) void*)l, 16, 0, 0);
}
// pack 16 adj values (2 row-subtiles x 2 key-halves x 4 keys) into bits
// bit (rt*2+nt)*4+q = adj[r0 + rt*16 + lr][joff + nt*16 + lg*4 + q]
__device__ __forceinline__ unsigned ldmask(const int* __restrict__ adj, size_t a0,
                                           size_t a1, int joff, int lg) {
  int4 a = *(const int4*)(adj + a0 + joff + lg * 4);
  int4 b = *(const int4*)(adj + a0 + joff + 16 + lg * 4);
  int4 c = *(const int4*)(adj + a1 + joff + lg * 4);
  int4 d = *(const int4*)(adj + a1 + joff + 16 + lg * 4);
  unsigned m = 0;
  m |= (a.x != 0) << 0;  m |= (a.y != 0) << 1;
  m |= (a.z != 0) << 2;  m |= (a.w != 0) << 3;
  m |= (b.x != 0) << 4;  m |= (b.y != 0) << 5;
  m |= (b.z != 0) << 6;  m |= (b.w != 0) << 7;
  m |= (c.x != 0) << 8;  m |= (c.y != 0) << 9;
  m |= (c.z != 0) << 10; m |= (c.w != 0) << 11;
  m |= (d.x != 0) << 12; m |= (d.y != 0) << 13;
  m |= (d.z != 0) << 14; m |= (d.w != 0) << 15;
  return m;
}

// ---- prep: count_k (blocks 0..31) | pack_wf (blocks 32..63) ---------------
__global__ __launch_bounds__(256) void prep_k(const float* __restrict__ W,
                                              const int* __restrict__ adj,
                                              unsigned short* __restrict__ Wf,
                                              int* __restrict__ kout) {
  const int bx = blockIdx.x, tid = threadIdx.x;
  if (bx < 32) {  // k = sum(adj[:,0] != 0)
    __shared__ int red[256];
    int gid = bx * 256 + tid;
    red[tid] = (adj[(size_t)gid * NN] != 0);
    __syncthreads();
    for (int off = 128; off; off >>= 1) {
      if (tid < off) red[tid] += red[tid + off];
      __syncthreads();
    }
    if (tid == 0) atomicAdd(kout, red[0]);
  } else {  // W -> bf16 B-frags
    int gid = (bx - 32) * 256 + tid;
    int l = gid & 63, f = gid >> 6, n16 = f >> 3, kk = f & 7;
    int lr = l & 15, lg = l >> 4;
    const float* src = W + (size_t)(n16 * 16 + lr) * DD + kk * 32 + lg * 8;
    float4 w0 = *(const float4*)src, w1 = *(const float4*)(src + 4);
    short8 o;
    o[0] = (short)f2bf(w0.x); o[1] = (short)f2bf(w0.y);
    o[2] = (short)f2bf(w0.z); o[3] = (short)f2bf(w0.w);
    o[4] = (short)f2bf(w1.x); o[5] = (short)f2bf(w1.y);
    o[6] = (short)f2bf(w1.z); o[7] = (short)f2bf(w1.w);
    *(short8*)(Wf + (size_t)gid * 8) = o;
  }
}

// ---- fused conv + h_new: h(f32) -> A-frags (regs) -> hQf store + GEMM -----
// hnV stored with k-permutation matching swapped-QK P register order.
__global__ __launch_bounds__(256) void hnew_k(const float* __restrict__ h,
                                              const unsigned short* __restrict__ Wf,
                                              const float* __restrict__ bias,
                                              unsigned short* __restrict__ hQf,
                                              unsigned short* __restrict__ hnb,
                                              unsigned short* __restrict__ hnV) {
  const int tid = threadIdx.x, w = tid >> 6, l = tid & 63, lr = l & 15, lg = l >> 4;
  const int row0 = blockIdx.x * 64 + w * 16;
  const int j16 = row0 >> 4;

  short8 a[8];
#pragma unroll
  for (int kk = 0; kk < 8; ++kk) {  // convert own rows f32 -> bf16 frags
    const float* src = h + (size_t)(row0 + lr) * DD + kk * 32 + lg * 8;
    float4 v0 = *(const float4*)src, v1 = *(const float4*)(src + 4);
    short8 o;
    o[0] = (short)f2bf(v0.x); o[1] = (short)f2bf(v0.y);
    o[2] = (short)f2bf(v0.z); o[3] = (short)f2bf(v0.w);
    o[4] = (short)f2bf(v1.x); o[5] = (short)f2bf(v1.y);
    o[6] = (short)f2bf(v1.z); o[7] = (short)f2bf(v1.w);
    a[kk] = o;
    *(short8*)(hQf + ((size_t)(j16 * 8 + kk) * 64 + l) * 8) = o;  // K/Q frags
  }

  f32x4 acc[16];
#pragma unroll
  for (int nt = 0; nt < 16; ++nt) acc[nt] = (f32x4){0.f, 0.f, 0.f, 0.f};
#pragma unroll
  for (int kk = 0; kk < 8; ++kk)
#pragma unroll
    for (int nt = 0; nt < 16; ++nt) {
      short8 bf = *(const short8*)(Wf + ((size_t)(nt * 8 + kk) * 64 + l) * 8);
      acc[nt] = mfma16(a[kk], bf, acc[nt]);
    }
  const int rowbase = row0 + lg * 4;                // 4 rows, q contiguous
  const int eb = ((rowbase >> 4) & 1) * 4;          // permuted elem base
#pragma unroll
  for (int nt = 0; nt < 16; ++nt) {
    const int col = nt * 16 + lr;
    const float bv = bias[col];
    unsigned short r16[4];
#pragma unroll
    for (int q = 0; q < 4; ++q) r16[q] = f2bf(acc[nt][q] + bv);
#pragma unroll
    for (int q = 0; q < 4; ++q) hnb[(size_t)(rowbase + q) * DD + col] = r16[q];
    ushort4 o4 = {r16[0], r16[1], r16[2], r16[3]};
    *(ushort4*)(hnV + (((size_t)(rowbase >> 5) * 16 + nt) * 64 + lg * 16 + lr) * 8 +
                eb) = o4;
  }
}

// ---- flash attention partials: column-split in 4-wave blocks --------------
// Grid (S=16 chunks, 128 tiles of 64 rows): chunk%8 = XCD. Wave w: row-group
// g=w>>1 (32 rows, 2 subtiles), col-half hc=w&1 (128 cols). Per iter/wave:
// 16 K-frag reads -> 32 QK MFMA; 8 V-frag reads -> 16 PV MFMA.
__global__ __launch_bounds__(256, 2) void attn_k(
    const unsigned short* __restrict__ hQf, const unsigned short* __restrict__ hnV,
    const int* __restrict__ adj, const int* __restrict__ kptr,
    float* __restrict__ pl, unsigned short* __restrict__ pO, int T) {
  __shared__ __align__(16) unsigned short sK[2][8192];  // 16KB x2
  __shared__ __align__(16) unsigned short sV[2][8192];  // 16KB x2

  const int tid = threadIdx.x, w = tid >> 6, l = tid & 63, lr = l & 15, lg = l >> 4;
  const int c = blockIdx.x, ty = blockIdx.y;
  const int i0 = ty * 64;
  const int kid = *kptr;
  if (i0 + 64 <= kid) return;  // whole tile identity: comb_k handles it

  const int g = w >> 1, hc = w & 1;
  const int r0 = i0 + g * 32;  // this wave's 32 rows (2 subtiles of 16)

  short8 qf[2][8];  // Q frags (B operand), 2 row-subtiles
#pragma unroll
  for (int rt = 0; rt < 2; ++rt)
#pragma unroll
    for (int kk = 0; kk < 8; ++kk)
      qf[rt][kk] =
          *(const short8*)(hQf + ((size_t)(((r0 >> 4) + rt) * 8 + kk) * 64 + l) * 8);

  f32x4 Oacc[2][8];  // [row-subtile][col-frag in this wave's half]
#pragma unroll
  for (int rt = 0; rt < 2; ++rt)
#pragma unroll
    for (int cn = 0; cn < 8; ++cn) Oacc[rt][cn] = (f32x4){0.f, 0.f, 0.f, 0.f};
  float lsum[2] = {0.f, 0.f};
  const float c1 = 0.09016844005556021f;  // log2(e)/sqrt(256)

  const size_t arow0 = (size_t)(r0 + lr) * NN;       // subtile-0 mask row
  const size_t arow1 = (size_t)(r0 + 16 + lr) * NN;  // subtile-1 mask row

  const int jt0 = c * T;

  // ---- prologue: stage tile jt0 into buf 0 (wave stages 4 segs each) ----
  {
    const unsigned short* srcK = hQf + (size_t)jt0 * 8192;
    const unsigned short* srcV = hnV + (size_t)jt0 * 8192;
#pragma unroll
    for (int s = 0; s < 4; ++s) {
      const int so = (w * 4 + s) * 512;
      gld16(srcK + so + l * 8, &sK[0][so]);
      gld16(srcV + so + l * 8, &sV[0][so]);
    }
  }
  unsigned mc = ldmask(adj, arow0, arow1, jt0 * 32, lg), mn = 0;
  __syncthreads();

  for (int t = 0; t < T; ++t) {
    const int cur = t & 1;
    if (t + 1 < T) {  // stage next tile + next packed mask
      const int jn = jt0 + t + 1;
      const unsigned short* srcK = hQf + (size_t)jn * 8192;
      const unsigned short* srcV = hnV + (size_t)jn * 8192;
#pragma unroll
      for (int s = 0; s < 4; ++s) {
        const int so = (w * 4 + s) * 512;
        gld16(srcK + so + l * 8, &sK[cur ^ 1][so]);
        gld16(srcV + so + l * 8, &sV[cur ^ 1][so]);
      }
      mn = ldmask(adj, arow0, arow1, jn * 32, lg);
    }

    // ---- S^T = K . Q^T (K=256): 16 K-frag reads -> 32 MFMAs (2x reuse) ----
    f32x4 S2[2][2];
#pragma unroll
    for (int rt = 0; rt < 2; ++rt)
#pragma unroll
      for (int nt = 0; nt < 2; ++nt) S2[rt][nt] = (f32x4){0.f, 0.f, 0.f, 0.f};
    __builtin_amdgcn_s_setprio(1);
#pragma unroll
    for (int kk = 0; kk < 8; ++kk)
#pragma unroll
      for (int nt = 0; nt < 2; ++nt) {
        short8 kf = *(const short8*)(&sK[cur][(nt * 8 + kk) * 512 + l * 8]);
        S2[0][nt] = mfma16(kf, qf[0][kk], S2[0][nt]);
        S2[1][nt] = mfma16(kf, qf[1][kk], S2[1][nt]);
      }
    __builtin_amdgcn_s_setprio(0);

    // ---- masked softmax numerators (pure sums), register P per subtile ----
    short8 pa[2];
#pragma unroll
    for (int rt = 0; rt < 2; ++rt) {
      float p[2][4];
#pragma unroll
      for (int nt = 0; nt < 2; ++nt)
#pragma unroll
        for (int q = 0; q < 4; ++q) {
          float sv = ((mc >> ((rt * 2 + nt) * 4 + q)) & 1u)
                         ? fminf(S2[rt][nt][q] * c1, 60.f)
                         : NEGB;
          p[nt][q] = __builtin_amdgcn_exp2f(sv);
        }
      lsum[rt] += ((p[0][0] + p[0][1]) + (p[0][2] + p[0][3])) +
                  ((p[1][0] + p[1][1]) + (p[1][2] + p[1][3]));
#pragma unroll
      for (int e = 0; e < 4; ++e) {
        pa[rt][e] = (short)f2bf(p[0][e]);
        pa[rt][e + 4] = (short)f2bf(p[1][e]);
      }
    }

    // ---- PV: 8 V-frag reads (this col-half) -> 16 MFMAs (2x reuse) ----
    __builtin_amdgcn_s_setprio(1);
#pragma unroll
    for (int cn = 0; cn < 8; ++cn) {
      short8 vf = *(const short8*)(&sV[cur][(hc * 8 + cn) * 512 + l * 8]);
      Oacc[0][cn] = mfma16(pa[0], vf, Oacc[0][cn]);
      Oacc[1][cn] = mfma16(pa[1], vf, Oacc[1][cn]);
    }
    __builtin_amdgcn_s_setprio(0);

    mc = mn;
    __syncthreads();  // staged tile complete + buffers safe to overwrite
  }

  // ---- reduce denominators across lg (shfl 16,32), write partials ----
#pragma unroll
  for (int rt = 0; rt < 2; ++rt) {
    float s = lsum[rt];
    s += __shfl_xor(s, 16);
    s += __shfl_xor(s, 32);
    if (hc == 0 && lg == 0) pl[(size_t)c * NN + r0 + rt * 16 + lr] = s;
  }
#pragma unroll
  for (int rt = 0; rt < 2; ++rt)
#pragma unroll
    for (int cn = 0; cn < 8; ++cn)
#pragma unroll
      for (int q = 0; q < 4; ++q) {
        int row = r0 + rt * 16 + lg * 4 + q;
        int col = hc * 128 + cn * 16 + lr;
        pO[((size_t)c * NN + row) * DD + col] = f2bf(Oacc[rt][cn][q]);
      }
}

// ---- combine chunks + epilogue: 4 rows/block, ushort4 lanes ---------------
__global__ __launch_bounds__(256) void comb_k(const float* __restrict__ pl,
                                              const unsigned short* __restrict__ pO,
                                              const unsigned short* __restrict__ hnb,
                                              const int* __restrict__ kptr,
                                              float* __restrict__ out, int S) {
  const int row = blockIdx.x * 4 + (threadIdx.x >> 6);
  const int col = (threadIdx.x & 63) * 4;
  const int kid = *kptr;
  ushort4 hv = *(const ushort4*)(hnb + (size_t)row * DD + col);
  float v0 = bf2f(hv.x), v1 = bf2f(hv.y), v2 = bf2f(hv.z), v3 = bf2f(hv.w);
  float4 r;
  if (row < kid) {
    r.x = v0; r.y = v1; r.z = v2; r.w = v3;
  } else {
    float L = 0.f, a0 = 0.f, a1 = 0.f, a2 = 0.f, a3 = 0.f;
    for (int cc = 0; cc < S; ++cc) {
      L += pl[(size_t)cc * NN + row];
      ushort4 ov = *(const ushort4*)(pO + ((size_t)cc * NN + row) * DD + col);
      a0 += bf2f(ov.x); a1 += bf2f(ov.y); a2 += bf2f(ov.z); a3 += bf2f(ov.w);
    }
    float inv = 0.5f / L;
    r.x = a0 * inv + 0.5f * v0; r.y = a1 * inv + 0.5f * v1;
    r.z = a2 * inv + 0.5f * v2; r.w = a3 * inv + 0.5f * v3;
  }
  r.x = fmaxf(r.x, 0.f); r.y = fmaxf(r.y, 0.f);
  r.z = fmaxf(r.z, 0.f); r.w = fmaxf(r.w, 0.f);
  *(float4*)(out + (size_t)row * DD + col) = r;
}

extern "C" void kernel_launch(void* const* d_in, const int* in_sizes, int n_in,
                              void* d_out, int out_size, void* d_ws, size_t ws_size,
                              hipStream_t stream) {
  const float* h = (const float*)d_in[0];
  const int* adj = (const int*)d_in[1];
  const float* W = (const float*)d_in[2];
  const float* b = (const float*)d_in[3];
  float* out = (float*)d_out;

  char* ws = (char*)d_ws;
  const size_t MB4 = (size_t)NN * DD * 2;  // 4 MiB
  int* kbuf = (int*)ws;
  unsigned short* hQf = (unsigned short*)(ws + 256);
  unsigned short* hnb = (unsigned short*)(ws + 256 + MB4);
  unsigned short* hnV = (unsigned short*)(ws + 256 + 2 * MB4);
  unsigned short* Wf = (unsigned short*)(ws + 256 + 3 * MB4);  // 128 KiB
  char* dyn = ws + 256 + 3 * MB4 + (256 << 10);

  size_t fixed = 256 + 3 * MB4 + (256 << 10);
  int S = 16;
  while (S > 1 && fixed + (size_t)S * NN * (DD * 2 + 4) > ws_size) S >>= 1;
  const int T = 256 / S;

  float* pl = (float*)dyn;
  unsigned short* pO = (unsigned short*)(pl + (size_t)S * NN);

  hipMemsetAsync(kbuf, 0, 4, stream);
  hipLaunchKernelGGL(prep_k, dim3(64), dim3(256), 0, stream, W, adj, Wf, kbuf);
  hipLaunchKernelGGL(hnew_k, dim3(NN / 64), dim3(256), 0, stream,
                     h, Wf, b, hQf, hnb, hnV);
  hipLaunchKernelGGL(attn_k, dim3(S, NN / 64), dim3(256), 0, stream,
                     hQf, hnV, adj, kbuf, pl, pO, T);
  hipLaunchKernelGGL(comb_k, dim3(NN / 4), dim3(256), 0, stream, pl, pO, hnb, kbuf, out, S);
}

// Round 15
// 126.391 us; speedup vs baseline: 1.2843x; 1.0967x over previous
//
#include <hip/hip_runtime.h>

// GAT layer fused, MI355X gfx950 — v14: v11's proven attn (16 rows/wave,
// swapped QK^T, register P, dbuf LDS, XCD-pinned chunks) + S=8 chunks
// (halved partial traffic) + hnew col-split (256 blocks). Pipeline:
// memset -> prep_k (count|packW) -> hnew_k -> attn_k -> comb_k.

typedef __attribute__((ext_vector_type(8))) short short8;   // 8 x bf16 (4 VGPR)
typedef __attribute__((ext_vector_type(4))) float f32x4;    // MFMA C/D frag

#define NN 8192
#define DD 256
#define NEGB -1.2983e16f  // -9e15 * log2(e): NEG_BIG in base-2 softmax domain

__device__ __forceinline__ unsigned short f2bf(float f) {
  unsigned u = __builtin_bit_cast(unsigned, f);
  u += 0x7FFFu + ((u >> 16) & 1u);  // RNE
  return (unsigned short)(u >> 16);
}
__device__ __forceinline__ float bf2f(unsigned short s) {
  unsigned u = ((unsigned)s) << 16;
  return __builtin_bit_cast(float, u);
}
__device__ __forceinline__ f32x4 mfma16(short8 a, short8 b, f32x4 c) {
  return __builtin_amdgcn_mfma_f32_16x16x32_bf16(a, b, c, 0, 0, 0);
}
// async global->LDS, 16B per lane; lds ptr wave-uniform base
__device__ __forceinline__ void gld16(const unsigned short* g, unsigned short* l) {
  __builtin_amdgcn_global_load_lds(
      (const __attribute__((address_space(1))) void*)g,
      (__attribute__((address_space(3))) void*)l, 16, 0, 0);
}

// ---- prep: count_k (blocks 0..31) | pack_wf (blocks 32..63) ---------------
__global__ __launch_bounds__(256) void prep_k(const float* __restrict__ W,
                                              const int* __restrict__ adj,
                                              unsigned short* __restrict__ Wf,
                                              int* __restrict__ kout) {
  const int bx = blockIdx.x, tid = threadIdx.x;
  if (bx < 32) {  // k = sum(adj[:,0] != 0)
    __shared__ int red[256];
    int gid = bx * 256 + tid;
    red[tid] = (adj[(size_t)gid * NN] != 0);
    __syncthreads();
    for (int off = 128; off; off >>= 1) {
      if (tid < off) red[tid] += red[tid + off];
      __syncthreads();
    }
    if (tid == 0) atomicAdd(kout, red[0]);
  } else {  // W -> bf16 B-frags
    int gid = (bx - 32) * 256 + tid;
    int l = gid & 63, f = gid >> 6, n16 = f >> 3, kk = f & 7;
    int lr = l & 15, lg = l >> 4;
    const float* src = W + (size_t)(n16 * 16 + lr) * DD + kk * 32 + lg * 8;
    float4 w0 = *(const float4*)src, w1 = *(const float4*)(src + 4);
    short8 o;
    o[0] = (short)f2bf(w0.x); o[1] = (short)f2bf(w0.y);
    o[2] = (short)f2bf(w0.z); o[3] = (short)f2bf(w0.w);
    o[4] = (short)f2bf(w1.x); o[5] = (short)f2bf(w1.y);
    o[6] = (short)f2bf(w1.z); o[7] = (short)f2bf(w1.w);
    *(short8*)(Wf + (size_t)gid * 8) = o;
  }
}

// ---- fused conv + h_new, col-split: 256 blocks (row-block x col-half) -----
// Conv runs in both halves (register need); hQf stored only by half 0.
// hnV stored with k-permutation matching swapped-QK P register order.
__global__ __launch_bounds__(256) void hnew_k(const float* __restrict__ h,
                                              const unsigned short* __restrict__ Wf,
                                              const float* __restrict__ bias,
                                              unsigned short* __restrict__ hQf,
                                              unsigned short* __restrict__ hnb,
                                              unsigned short* __restrict__ hnV) {
  const int tid = threadIdx.x, w = tid >> 6, l = tid & 63, lr = l & 15, lg = l >> 4;
  const int row0 = (blockIdx.x >> 1) * 64 + w * 16;
  const int nt0 = (blockIdx.x & 1) * 8;
  const int j16 = row0 >> 4;

  short8 a[8];
#pragma unroll
  for (int kk = 0; kk < 8; ++kk) {  // convert own rows f32 -> bf16 frags
    const float* src = h + (size_t)(row0 + lr) * DD + kk * 32 + lg * 8;
    float4 v0 = *(const float4*)src, v1 = *(const float4*)(src + 4);
    short8 o;
    o[0] = (short)f2bf(v0.x); o[1] = (short)f2bf(v0.y);
    o[2] = (short)f2bf(v0.z); o[3] = (short)f2bf(v0.w);
    o[4] = (short)f2bf(v1.x); o[5] = (short)f2bf(v1.y);
    o[6] = (short)f2bf(v1.z); o[7] = (short)f2bf(v1.w);
    a[kk] = o;
    if (nt0 == 0)
      *(short8*)(hQf + ((size_t)(j16 * 8 + kk) * 64 + l) * 8) = o;  // K/Q frags
  }

  f32x4 acc[8];
#pragma unroll
  for (int nt = 0; nt < 8; ++nt) acc[nt] = (f32x4){0.f, 0.f, 0.f, 0.f};
#pragma unroll
  for (int kk = 0; kk < 8; ++kk)
#pragma unroll
    for (int nt = 0; nt < 8; ++nt) {
      short8 bf = *(const short8*)(Wf + ((size_t)((nt0 + nt) * 8 + kk) * 64 + l) * 8);
      acc[nt] = mfma16(a[kk], bf, acc[nt]);
    }
  const int rowbase = row0 + lg * 4;                // 4 rows, q contiguous
  const int eb = ((rowbase >> 4) & 1) * 4;          // permuted elem base
#pragma unroll
  for (int nt = 0; nt < 8; ++nt) {
    const int col = (nt0 + nt) * 16 + lr;
    const float bv = bias[col];
    unsigned short r16[4];
#pragma unroll
    for (int q = 0; q < 4; ++q) r16[q] = f2bf(acc[nt][q] + bv);
#pragma unroll
    for (int q = 0; q < 4; ++q) hnb[(size_t)(rowbase + q) * DD + col] = r16[q];
    ushort4 o4 = {r16[0], r16[1], r16[2], r16[3]};
    *(ushort4*)(hnV + (((size_t)(rowbase >> 5) * 16 + nt0 + nt) * 64 + lg * 16 + lr) *
                          8 + eb) = o4;
  }
}

// ---- flash attention partials: swapped QK^T, register-only P --------------
// Grid (S=8 chunks, 128 tiles of 64 rows): chunk%8 = XCD (L2-pinned K/V).
// 4 waves x 16 rows; dbuf LDS; 2x unrolled; 1 barrier/iter.
// S2 = mfma(Kfrag, Qfrag) -> lane (lg,lr) holds P[lr][nt*16+4lg+q]; PV A-frag
// pa[e] = (e<4) ? p[0][e] : p[1][e-4] matches hnV's permuted k-order.
__global__ __launch_bounds__(256, 2) void attn_k(
    const unsigned short* __restrict__ hQf, const unsigned short* __restrict__ hnV,
    const int* __restrict__ adj, const int* __restrict__ kptr,
    float* __restrict__ pl, unsigned short* __restrict__ pO, int T) {
  __shared__ __align__(16) unsigned short sK[2][8192];   // 16KB x2
  __shared__ __align__(16) unsigned short sV[2][8192];   // 16KB x2

  const int tid = threadIdx.x, w = tid >> 6, l = tid & 63, lr = l & 15, lg = l >> 4;
  const int c = blockIdx.x, ty = blockIdx.y;
  const int i0 = ty * 64;
  const int kid = *kptr;
  if (i0 + 64 <= kid) return;  // whole tile identity: comb_k handles it

  const int r0 = i0 + w * 16;  // this wave's 16 rows

  short8 qf[8];  // Q frags (used as B operand; same lane layout as A)
#pragma unroll
  for (int kk = 0; kk < 8; ++kk)
    qf[kk] = *(const short8*)(hQf + ((size_t)((r0 >> 4) * 8 + kk) * 64 + l) * 8);

  f32x4 Oacc[16];
#pragma unroll
  for (int nt = 0; nt < 16; ++nt) Oacc[nt] = (f32x4){0.f, 0.f, 0.f, 0.f};
  float lsum = 0.f;                       // all 8 p/iter belong to row lr
  const float c1 = 0.09016844005556021f;  // log2(e)/sqrt(256)

  const size_t arow = (size_t)(r0 + lr) * NN;  // this lane's mask row

  const int jt0 = c * T;

  // ---- prologue: stage tile jt0 into buf 0, masks into avA (int4 x2) ----
  {
    const unsigned short* srcK = hQf + (size_t)jt0 * 8192;
    const unsigned short* srcV = hnV + (size_t)jt0 * 8192;
#pragma unroll
    for (int s = 0; s < 4; ++s) {
      const int so = (w * 4 + s) * 512;
      gld16(srcK + so + l * 8, &sK[0][so]);
      gld16(srcV + so + l * 8, &sV[0][so]);
    }
  }
  int avA[8], avB[8];
  {
    int4 t0 = *(const int4*)(adj + arow + jt0 * 32 + lg * 4);
    int4 t1 = *(const int4*)(adj + arow + jt0 * 32 + 16 + lg * 4);
    avA[0] = t0.x; avA[1] = t0.y; avA[2] = t0.z; avA[3] = t0.w;
    avA[4] = t1.x; avA[5] = t1.y; avA[6] = t1.z; avA[7] = t1.w;
  }
  __syncthreads();

#define ATTN_ITER(T_IDX, CUR, MC, MN)                                          \
  {                                                                            \
    const int t_ = (T_IDX);                                                    \
    if (t_ + 1 < T) { /* stage next tile + next masks */                       \
      const int jn = jt0 + t_ + 1;                                             \
      const unsigned short* srcK = hQf + (size_t)jn * 8192;                    \
      const unsigned short* srcV = hnV + (size_t)jn * 8192;                    \
      _Pragma("unroll") for (int s = 0; s < 4; ++s) {                          \
        const int so = (w * 4 + s) * 512;                                      \
        gld16(srcK + so + l * 8, &sK[(CUR) ^ 1][so]);                          \
        gld16(srcV + so + l * 8, &sV[(CUR) ^ 1][so]);                          \
      }                                                                        \
      int4 t0 = *(const int4*)(adj + arow + jn * 32 + lg * 4);                 \
      int4 t1 = *(const int4*)(adj + arow + jn * 32 + 16 + lg * 4);            \
      MN[0] = t0.x; MN[1] = t0.y; MN[2] = t0.z; MN[3] = t0.w;                  \
      MN[4] = t1.x; MN[5] = t1.y; MN[6] = t1.z; MN[7] = t1.w;                  \
    }                                                                          \
    f32x4 S2[2];                                                               \
    S2[0] = (f32x4){0.f, 0.f, 0.f, 0.f};                                       \
    S2[1] = (f32x4){0.f, 0.f, 0.f, 0.f};                                       \
    __builtin_amdgcn_s_setprio(1);                                             \
    _Pragma("unroll") for (int kk = 0; kk < 8; ++kk)                           \
      _Pragma("unroll") for (int nt = 0; nt < 2; ++nt) {                       \
        short8 kf = *(const short8*)(&sK[(CUR)][(nt * 8 + kk) * 512 + l * 8]); \
        S2[nt] = mfma16(kf, qf[kk], S2[nt]); /* swapped: S^T */                \
      }                                                                        \
    __builtin_amdgcn_s_setprio(0);                                             \
    float p[2][4];                                                             \
    _Pragma("unroll") for (int nt = 0; nt < 2; ++nt)                           \
      _Pragma("unroll") for (int q = 0; q < 4; ++q) {                          \
        float sv = MC[nt * 4 + q] ? fminf(S2[nt][q] * c1, 60.f) : NEGB;        \
        p[nt][q] = __builtin_amdgcn_exp2f(sv);                                 \
      }                                                                        \
    lsum += ((p[0][0] + p[0][1]) + (p[0][2] + p[0][3])) +                      \
            ((p[1][0] + p[1][1]) + (p[1][2] + p[1][3]));                       \
    short8 pa;                                                                 \
    _Pragma("unroll") for (int e = 0; e < 4; ++e) {                            \
      pa[e] = (short)f2bf(p[0][e]);                                            \
      pa[e + 4] = (short)f2bf(p[1][e]);                                        \
    }                                                                          \
    __builtin_amdgcn_s_setprio(1);                                             \
    _Pragma("unroll") for (int cnt = 0; cnt < 16; ++cnt) {                     \
      short8 vf = *(const short8*)(&sV[(CUR)][cnt * 512 + l * 8]);             \
      Oacc[cnt] = mfma16(pa, vf, Oacc[cnt]);                                   \
    }                                                                          \
    __builtin_amdgcn_s_setprio(0);                                             \
    __syncthreads();                                                           \
  }

  for (int tt = 0; tt < T; tt += 2) {
    ATTN_ITER(tt, 0, avA, avB);      // compute buf0/avA, stage buf1/avB
    ATTN_ITER(tt + 1, 1, avB, avA);  // compute buf1/avB, stage buf0/avA
  }
#undef ATTN_ITER

  // ---- reduce denominators across lg (shfl 16,32), write partials ----
  lsum += __shfl_xor(lsum, 16);
  lsum += __shfl_xor(lsum, 32);
  if (lg == 0) pl[(size_t)c * NN + r0 + lr] = lsum;
#pragma unroll
  for (int cnt = 0; cnt < 16; ++cnt)
#pragma unroll
    for (int q = 0; q < 4; ++q) {
      int row = r0 + lg * 4 + q;
      pO[((size_t)c * NN + row) * DD + cnt * 16 + lr] = f2bf(Oacc[cnt][q]);
    }
}

// ---- combine chunks + epilogue: 4 rows/block, ushort4 lanes ---------------
__global__ __launch_bounds__(256) void comb_k(const float* __restrict__ pl,
                                              const unsigned short* __restrict__ pO,
                                              const unsigned short* __restrict__ hnb,
                                              const int* __restrict__ kptr,
                                              float* __restrict__ out, int S) {
  const int row = blockIdx.x * 4 + (threadIdx.x >> 6);
  const int col = (threadIdx.x & 63) * 4;
  const int kid = *kptr;
  ushort4 hv = *(const ushort4*)(hnb + (size_t)row * DD + col);
  float v0 = bf2f(hv.x), v1 = bf2f(hv.y), v2 = bf2f(hv.z), v3 = bf2f(hv.w);
  float4 r;
  if (row < kid) {
    r.x = v0; r.y = v1; r.z = v2; r.w = v3;
  } else {
    float L = 0.f, a0 = 0.f, a1 = 0.f, a2 = 0.f, a3 = 0.f;
    for (int cc = 0; cc < S; ++cc) {
      L += pl[(size_t)cc * NN + row];
      ushort4 ov = *(const ushort4*)(pO + ((size_t)cc * NN + row) * DD + col);
      a0 += bf2f(ov.x); a1 += bf2f(ov.y); a2 += bf2f(ov.z); a3 += bf2f(ov.w);
    }
    float inv = 0.5f / L;
    r.x = a0 * inv + 0.5f * v0; r.y = a1 * inv + 0.5f * v1;
    r.z = a2 * inv + 0.5f * v2; r.w = a3 * inv + 0.5f * v3;
  }
  r.x = fmaxf(r.x, 0.f); r.y = fmaxf(r.y, 0.f);
  r.z = fmaxf(r.z, 0.f); r.w = fmaxf(r.w, 0.f);
  *(float4*)(out + (size_t)row * DD + col) = r;
}

extern "C" void kernel_launch(void* const* d_in, const int* in_sizes, int n_in,
                              void* d_out, int out_size, void* d_ws, size_t ws_size,
                              hipStream_t stream) {
  const float* h = (const float*)d_in[0];
  const int* adj = (const int*)d_in[1];
  const float* W = (const float*)d_in[2];
  const float* b = (const float*)d_in[3];
  float* out = (float*)d_out;

  char* ws = (char*)d_ws;
  const size_t MB4 = (size_t)NN * DD * 2;  // 4 MiB
  int* kbuf = (int*)ws;
  unsigned short* hQf = (unsigned short*)(ws + 256);
  unsigned short* hnb = (unsigned short*)(ws + 256 + MB4);
  unsigned short* hnV = (unsigned short*)(ws + 256 + 2 * MB4);
  unsigned short* Wf = (unsigned short*)(ws + 256 + 3 * MB4);  // 128 KiB
  char* dyn = ws + 256 + 3 * MB4 + (256 << 10);

  size_t fixed = 256 + 3 * MB4 + (256 << 10);
  int S = 8;
  while (S > 1 && fixed + (size_t)S * NN * (DD * 2 + 4) > ws_size) S >>= 1;
  const int T = 256 / S;

  float* pl = (float*)dyn;
  unsigned short* pO = (unsigned short*)(pl + (size_t)S * NN);

  hipMemsetAsync(kbuf, 0, 4, stream);
  hipLaunchKernelGGL(prep_k, dim3(64), dim3(256), 0, stream, W, adj, Wf, kbuf);
  hipLaunchKernelGGL(hnew_k, dim3(256), dim3(256), 0, stream,
                     h, Wf, b, hQf, hnb, hnV);
  hipLaunchKernelGGL(attn_k, dim3(S, NN / 64), dim3(256), 0, stream,
                     hQf, hnV, adj, kbuf, pl, pO, T);
  hipLaunchKernelGGL(comb_k, dim3(NN / 4), dim3(256), 0, stream, pl, pO, hnb, kbuf, out, S);
}

// Round 16
// 110.862 us; speedup vs baseline: 1.4642x; 1.1401x over previous
//
#include <hip/hip_runtime.h>

// GAT layer fused, MI355X gfx950 — v15: consolidation. v11's proven attn
// (S=16 chunks, 16 rows/wave, swapped QK^T, register P, dbuf LDS, XCD-pinned)
// + v14's col-split hnew (256 blocks). memset -> prep -> hnew -> attn -> comb.

typedef __attribute__((ext_vector_type(8))) short short8;   // 8 x bf16 (4 VGPR)
typedef __attribute__((ext_vector_type(4))) float f32x4;    // MFMA C/D frag

#define NN 8192
#define DD 256
#define NEGB -1.2983e16f  // -9e15 * log2(e): NEG_BIG in base-2 softmax domain

__device__ __forceinline__ unsigned short f2bf(float f) {
  unsigned u = __builtin_bit_cast(unsigned, f);
  u += 0x7FFFu + ((u >> 16) & 1u);  // RNE
  return (unsigned short)(u >> 16);
}
__device__ __forceinline__ float bf2f(unsigned short s) {
  unsigned u = ((unsigned)s) << 16;
  return __builtin_bit_cast(float, u);
}
__device__ __forceinline__ f32x4 mfma16(short8 a, short8 b, f32x4 c) {
  return __builtin_amdgcn_mfma_f32_16x16x32_bf16(a, b, c, 0, 0, 0);
}
// async global->LDS, 16B per lane; lds ptr wave-uniform base
__device__ __forceinline__ void gld16(const unsigned short* g, unsigned short* l) {
  __builtin_amdgcn_global_load_lds(
      (const __attribute__((address_space(1))) void*)g,
      (__attribute__((address_space(3))) void*)l, 16, 0, 0);
}

// ---- prep: count_k (blocks 0..31) | pack_wf (blocks 32..63) ---------------
__global__ __launch_bounds__(256) void prep_k(const float* __restrict__ W,
                                              const int* __restrict__ adj,
                                              unsigned short* __restrict__ Wf,
                                              int* __restrict__ kout) {
  const int bx = blockIdx.x, tid = threadIdx.x;
  if (bx < 32) {  // k = sum(adj[:,0] != 0)
    __shared__ int red[256];
    int gid = bx * 256 + tid;
    red[tid] = (adj[(size_t)gid * NN] != 0);
    __syncthreads();
    for (int off = 128; off; off >>= 1) {
      if (tid < off) red[tid] += red[tid + off];
      __syncthreads();
    }
    if (tid == 0) atomicAdd(kout, red[0]);
  } else {  // W -> bf16 B-frags
    int gid = (bx - 32) * 256 + tid;
    int l = gid & 63, f = gid >> 6, n16 = f >> 3, kk = f & 7;
    int lr = l & 15, lg = l >> 4;
    const float* src = W + (size_t)(n16 * 16 + lr) * DD + kk * 32 + lg * 8;
    float4 w0 = *(const float4*)src, w1 = *(const float4*)(src + 4);
    short8 o;
    o[0] = (short)f2bf(w0.x); o[1] = (short)f2bf(w0.y);
    o[2] = (short)f2bf(w0.z); o[3] = (short)f2bf(w0.w);
    o[4] = (short)f2bf(w1.x); o[5] = (short)f2bf(w1.y);
    o[6] = (short)f2bf(w1.z); o[7] = (short)f2bf(w1.w);
    *(short8*)(Wf + (size_t)gid * 8) = o;
  }
}

// ---- fused conv + h_new, col-split: 256 blocks (row-block x col-half) -----
// Conv runs in both halves (register need); hQf stored only by half 0.
// hnV stored with k-permutation matching swapped-QK P register order.
__global__ __launch_bounds__(256) void hnew_k(const float* __restrict__ h,
                                              const unsigned short* __restrict__ Wf,
                                              const float* __restrict__ bias,
                                              unsigned short* __restrict__ hQf,
                                              unsigned short* __restrict__ hnb,
                                              unsigned short* __restrict__ hnV) {
  const int tid = threadIdx.x, w = tid >> 6, l = tid & 63, lr = l & 15, lg = l >> 4;
  const int row0 = (blockIdx.x >> 1) * 64 + w * 16;
  const int nt0 = (blockIdx.x & 1) * 8;
  const int j16 = row0 >> 4;

  short8 a[8];
#pragma unroll
  for (int kk = 0; kk < 8; ++kk) {  // convert own rows f32 -> bf16 frags
    const float* src = h + (size_t)(row0 + lr) * DD + kk * 32 + lg * 8;
    float4 v0 = *(const float4*)src, v1 = *(const float4*)(src + 4);
    short8 o;
    o[0] = (short)f2bf(v0.x); o[1] = (short)f2bf(v0.y);
    o[2] = (short)f2bf(v0.z); o[3] = (short)f2bf(v0.w);
    o[4] = (short)f2bf(v1.x); o[5] = (short)f2bf(v1.y);
    o[6] = (short)f2bf(v1.z); o[7] = (short)f2bf(v1.w);
    a[kk] = o;
    if (nt0 == 0)
      *(short8*)(hQf + ((size_t)(j16 * 8 + kk) * 64 + l) * 8) = o;  // K/Q frags
  }

  f32x4 acc[8];
#pragma unroll
  for (int nt = 0; nt < 8; ++nt) acc[nt] = (f32x4){0.f, 0.f, 0.f, 0.f};
#pragma unroll
  for (int kk = 0; kk < 8; ++kk)
#pragma unroll
    for (int nt = 0; nt < 8; ++nt) {
      short8 bf = *(const short8*)(Wf + ((size_t)((nt0 + nt) * 8 + kk) * 64 + l) * 8);
      acc[nt] = mfma16(a[kk], bf, acc[nt]);
    }
  const int rowbase = row0 + lg * 4;                // 4 rows, q contiguous
  const int eb = ((rowbase >> 4) & 1) * 4;          // permuted elem base
#pragma unroll
  for (int nt = 0; nt < 8; ++nt) {
    const int col = (nt0 + nt) * 16 + lr;
    const float bv = bias[col];
    unsigned short r16[4];
#pragma unroll
    for (int q = 0; q < 4; ++q) r16[q] = f2bf(acc[nt][q] + bv);
#pragma unroll
    for (int q = 0; q < 4; ++q) hnb[(size_t)(rowbase + q) * DD + col] = r16[q];
    ushort4 o4 = {r16[0], r16[1], r16[2], r16[3]};
    *(ushort4*)(hnV + (((size_t)(rowbase >> 5) * 16 + nt0 + nt) * 64 + lg * 16 + lr) *
                          8 + eb) = o4;
  }
}

// ---- flash attention partials: swapped QK^T, register-only P --------------
// Grid (S=16 chunks, 128 tiles of 64 rows): chunk%8 = XCD (L2-pinned K/V).
// 4 waves x 16 rows; dbuf LDS; 2x unrolled; 1 barrier/iter.
// S2 = mfma(Kfrag, Qfrag) -> lane (lg,lr) holds P[lr][nt*16+4lg+q]; PV A-frag
// pa[e] = (e<4) ? p[0][e] : p[1][e-4] matches hnV's permuted k-order.
__global__ __launch_bounds__(256, 2) void attn_k(
    const unsigned short* __restrict__ hQf, const unsigned short* __restrict__ hnV,
    const int* __restrict__ adj, const int* __restrict__ kptr,
    float* __restrict__ pl, unsigned short* __restrict__ pO, int T) {
  __shared__ __align__(16) unsigned short sK[2][8192];   // 16KB x2
  __shared__ __align__(16) unsigned short sV[2][8192];   // 16KB x2

  const int tid = threadIdx.x, w = tid >> 6, l = tid & 63, lr = l & 15, lg = l >> 4;
  const int c = blockIdx.x, ty = blockIdx.y;
  const int i0 = ty * 64;
  const int kid = *kptr;
  if (i0 + 64 <= kid) return;  // whole tile identity: comb_k handles it

  const int r0 = i0 + w * 16;  // this wave's 16 rows

  short8 qf[8];  // Q frags (used as B operand; same lane layout as A)
#pragma unroll
  for (int kk = 0; kk < 8; ++kk)
    qf[kk] = *(const short8*)(hQf + ((size_t)((r0 >> 4) * 8 + kk) * 64 + l) * 8);

  f32x4 Oacc[16];
#pragma unroll
  for (int nt = 0; nt < 16; ++nt) Oacc[nt] = (f32x4){0.f, 0.f, 0.f, 0.f};
  float lsum = 0.f;                       // all 8 p/iter belong to row lr
  const float c1 = 0.09016844005556021f;  // log2(e)/sqrt(256)

  const size_t arow = (size_t)(r0 + lr) * NN;  // this lane's mask row

  const int jt0 = c * T;

  // ---- prologue: stage tile jt0 into buf 0, masks into avA (int4 x2) ----
  {
    const unsigned short* srcK = hQf + (size_t)jt0 * 8192;
    const unsigned short* srcV = hnV + (size_t)jt0 * 8192;
#pragma unroll
    for (int s = 0; s < 4; ++s) {
      const int so = (w * 4 + s) * 512;
      gld16(srcK + so + l * 8, &sK[0][so]);
      gld16(srcV + so + l * 8, &sV[0][so]);
    }
  }
  int avA[8], avB[8];
  {
    int4 t0 = *(const int4*)(adj + arow + jt0 * 32 + lg * 4);
    int4 t1 = *(const int4*)(adj + arow + jt0 * 32 + 16 + lg * 4);
    avA[0] = t0.x; avA[1] = t0.y; avA[2] = t0.z; avA[3] = t0.w;
    avA[4] = t1.x; avA[5] = t1.y; avA[6] = t1.z; avA[7] = t1.w;
  }
  __syncthreads();

#define ATTN_ITER(T_IDX, CUR, MC, MN)                                          \
  {                                                                            \
    const int t_ = (T_IDX);                                                    \
    if (t_ + 1 < T) { /* stage next tile + next masks */                       \
      const int jn = jt0 + t_ + 1;                                             \
      const unsigned short* srcK = hQf + (size_t)jn * 8192;                    \
      const unsigned short* srcV = hnV + (size_t)jn * 8192;                    \
      _Pragma("unroll") for (int s = 0; s < 4; ++s) {                          \
        const int so = (w * 4 + s) * 512;                                      \
        gld16(srcK + so + l * 8, &sK[(CUR) ^ 1][so]);                          \
        gld16(srcV + so + l * 8, &sV[(CUR) ^ 1][so]);                          \
      }                                                                        \
      int4 t0 = *(const int4*)(adj + arow + jn * 32 + lg * 4);                 \
      int4 t1 = *(const int4*)(adj + arow + jn * 32 + 16 + lg * 4);            \
      MN[0] = t0.x; MN[1] = t0.y; MN[2] = t0.z; MN[3] = t0.w;                  \
      MN[4] = t1.x; MN[5] = t1.y; MN[6] = t1.z; MN[7] = t1.w;                  \
    }                                                                          \
    f32x4 S2[2];                                                               \
    S2[0] = (f32x4){0.f, 0.f, 0.f, 0.f};                                       \
    S2[1] = (f32x4){0.f, 0.f, 0.f, 0.f};                                       \
    __builtin_amdgcn_s_setprio(1);                                             \
    _Pragma("unroll") for (int kk = 0; kk < 8; ++kk)                           \
      _Pragma("unroll") for (int nt = 0; nt < 2; ++nt) {                       \
        short8 kf = *(const short8*)(&sK[(CUR)][(nt * 8 + kk) * 512 + l * 8]); \
        S2[nt] = mfma16(kf, qf[kk], S2[nt]); /* swapped: S^T */                \
      }                                                                        \
    __builtin_amdgcn_s_setprio(0);                                             \
    float p[2][4];                                                             \
    _Pragma("unroll") for (int nt = 0; nt < 2; ++nt)                           \
      _Pragma("unroll") for (int q = 0; q < 4; ++q) {                          \
        float sv = MC[nt * 4 + q] ? fminf(S2[nt][q] * c1, 60.f) : NEGB;        \
        p[nt][q] = __builtin_amdgcn_exp2f(sv);                                 \
      }                                                                        \
    lsum += ((p[0][0] + p[0][1]) + (p[0][2] + p[0][3])) +                      \
            ((p[1][0] + p[1][1]) + (p[1][2] + p[1][3]));                       \
    short8 pa;                                                                 \
    _Pragma("unroll") for (int e = 0; e < 4; ++e) {                            \
      pa[e] = (short)f2bf(p[0][e]);                                            \
      pa[e + 4] = (short)f2bf(p[1][e]);                                        \
    }                                                                          \
    __builtin_amdgcn_s_setprio(1);                                             \
    _Pragma("unroll") for (int cnt = 0; cnt < 16; ++cnt) {                     \
      short8 vf = *(const short8*)(&sV[(CUR)][cnt * 512 + l * 8]);             \
      Oacc[cnt] = mfma16(pa, vf, Oacc[cnt]);                                   \
    }                                                                          \
    __builtin_amdgcn_s_setprio(0);                                             \
    __syncthreads();                                                           \
  }

  for (int tt = 0; tt < T; tt += 2) {
    ATTN_ITER(tt, 0, avA, avB);      // compute buf0/avA, stage buf1/avB
    ATTN_ITER(tt + 1, 1, avB, avA);  // compute buf1/avB, stage buf0/avA
  }
#undef ATTN_ITER

  // ---- reduce denominators across lg (shfl 16,32), write partials ----
  lsum += __shfl_xor(lsum, 16);
  lsum += __shfl_xor(lsum, 32);
  if (lg == 0) pl[(size_t)c * NN + r0 + lr] = lsum;
#pragma unroll
  for (int cnt = 0; cnt < 16; ++cnt)
#pragma unroll
    for (int q = 0; q < 4; ++q) {
      int row = r0 + lg * 4 + q;
      pO[((size_t)c * NN + row) * DD + cnt * 16 + lr] = f2bf(Oacc[cnt][q]);
    }
}

// ---- combine chunks + epilogue: 4 rows/block, ushort4 lanes ---------------
__global__ __launch_bounds__(256) void comb_k(const float* __restrict__ pl,
                                              const unsigned short* __restrict__ pO,
                                              const unsigned short* __restrict__ hnb,
                                              const int* __restrict__ kptr,
                                              float* __restrict__ out, int S) {
  const int row = blockIdx.x * 4 + (threadIdx.x >> 6);
  const int col = (threadIdx.x & 63) * 4;
  const int kid = *kptr;
  ushort4 hv = *(const ushort4*)(hnb + (size_t)row * DD + col);
  float v0 = bf2f(hv.x), v1 = bf2f(hv.y), v2 = bf2f(hv.z), v3 = bf2f(hv.w);
  float4 r;
  if (row < kid) {
    r.x = v0; r.y = v1; r.z = v2; r.w = v3;
  } else {
    float L = 0.f, a0 = 0.f, a1 = 0.f, a2 = 0.f, a3 = 0.f;
    for (int cc = 0; cc < S; ++cc) {
      L += pl[(size_t)cc * NN + row];
      ushort4 ov = *(const ushort4*)(pO + ((size_t)cc * NN + row) * DD + col);
      a0 += bf2f(ov.x); a1 += bf2f(ov.y); a2 += bf2f(ov.z); a3 += bf2f(ov.w);
    }
    float inv = 0.5f / L;
    r.x = a0 * inv + 0.5f * v0; r.y = a1 * inv + 0.5f * v1;
    r.z = a2 * inv + 0.5f * v2; r.w = a3 * inv + 0.5f * v3;
  }
  r.x = fmaxf(r.x, 0.f); r.y = fmaxf(r.y, 0.f);
  r.z = fmaxf(r.z, 0.f); r.w = fmaxf(r.w, 0.f);
  *(float4*)(out + (size_t)row * DD + col) = r;
}

extern "C" void kernel_launch(void* const* d_in, const int* in_sizes, int n_in,
                              void* d_out, int out_size, void* d_ws, size_t ws_size,
                              hipStream_t stream) {
  const float* h = (const float*)d_in[0];
  const int* adj = (const int*)d_in[1];
  const float* W = (const float*)d_in[2];
  const float* b = (const float*)d_in[3];
  float* out = (float*)d_out;

  char* ws = (char*)d_ws;
  const size_t MB4 = (size_t)NN * DD * 2;  // 4 MiB
  int* kbuf = (int*)ws;
  unsigned short* hQf = (unsigned short*)(ws + 256);
  unsigned short* hnb = (unsigned short*)(ws + 256 + MB4);
  unsigned short* hnV = (unsigned short*)(ws + 256 + 2 * MB4);
  unsigned short* Wf = (unsigned short*)(ws + 256 + 3 * MB4);  // 128 KiB
  char* dyn = ws + 256 + 3 * MB4 + (256 << 10);

  size_t fixed = 256 + 3 * MB4 + (256 << 10);
  int S = 16;
  while (S > 1 && fixed + (size_t)S * NN * (DD * 2 + 4) > ws_size) S >>= 1;
  const int T = 256 / S;

  float* pl = (float*)dyn;
  unsigned short* pO = (unsigned short*)(pl + (size_t)S * NN);

  hipMemsetAsync(kbuf, 0, 4, stream);
  hipLaunchKernelGGL(prep_k, dim3(64), dim3(256), 0, stream, W, adj, Wf, kbuf);
  hipLaunchKernelGGL(hnew_k, dim3(256), dim3(256), 0, stream,
                     h, Wf, b, hQf, hnb, hnV);
  hipLaunchKernelGGL(attn_k, dim3(S, NN / 64), dim3(256), 0, stream,
                     hQf, hnV, adj, kbuf, pl, pO, T);
  hipLaunchKernelGGL(comb_k, dim3(NN / 4), dim3(256), 0, stream, pl, pO, hnb, kbuf, out, S);
}

// Round 17
// 110.014 us; speedup vs baseline: 1.4755x; 1.0077x over previous
//
#include <hip/hip_runtime.h>

// GAT layer fused, MI355X gfx950 — v16 (final consolidation): v11's attn
// (S=16, 16 rows/wave, swapped QK^T, register P, dbuf LDS, XCD-pinned) +
// v11's fused hnew + single-block no-atomic count (no memset launch).
// Pipeline: prep_k -> hnew_k -> attn_k -> comb_k  (4 launches).

typedef __attribute__((ext_vector_type(8))) short short8;   // 8 x bf16 (4 VGPR)
typedef __attribute__((ext_vector_type(4))) float f32x4;    // MFMA C/D frag

#define NN 8192
#define DD 256
#define NEGB -1.2983e16f  // -9e15 * log2(e): NEG_BIG in base-2 softmax domain

__device__ __forceinline__ unsigned short f2bf(float f) {
  unsigned u = __builtin_bit_cast(unsigned, f);
  u += 0x7FFFu + ((u >> 16) & 1u);  // RNE
  return (unsigned short)(u >> 16);
}
__device__ __forceinline__ float bf2f(unsigned short s) {
  unsigned u = ((unsigned)s) << 16;
  return __builtin_bit_cast(float, u);
}
__device__ __forceinline__ f32x4 mfma16(short8 a, short8 b, f32x4 c) {
  return __builtin_amdgcn_mfma_f32_16x16x32_bf16(a, b, c, 0, 0, 0);
}
// async global->LDS, 16B per lane; lds ptr wave-uniform base
__device__ __forceinline__ void gld16(const unsigned short* g, unsigned short* l) {
  __builtin_amdgcn_global_load_lds(
      (const __attribute__((address_space(1))) void*)g,
      (__attribute__((address_space(3))) void*)l, 16, 0, 0);
}

// ---- prep: block 0 = full count (no atomic); blocks 1..32 = pack_wf -------
__global__ __launch_bounds__(256) void prep_k(const float* __restrict__ W,
                                              const int* __restrict__ adj,
                                              unsigned short* __restrict__ Wf,
                                              int* __restrict__ kout) {
  const int bx = blockIdx.x, tid = threadIdx.x;
  if (bx == 0) {  // k = sum(adj[:,0] != 0), one block, no memset needed
    __shared__ int red[256];
    int s = 0;
    for (int it = 0; it < 32; ++it) s += (adj[(size_t)(it * 256 + tid) * NN] != 0);
    red[tid] = s;
    __syncthreads();
    for (int off = 128; off; off >>= 1) {
      if (tid < off) red[tid] += red[tid + off];
      __syncthreads();
    }
    if (tid == 0) *kout = red[0];
  } else {  // W -> bf16 B-frags
    int gid = (bx - 1) * 256 + tid;
    int l = gid & 63, f = gid >> 6, n16 = f >> 3, kk = f & 7;
    int lr = l & 15, lg = l >> 4;
    const float* src = W + (size_t)(n16 * 16 + lr) * DD + kk * 32 + lg * 8;
    float4 w0 = *(const float4*)src, w1 = *(const float4*)(src + 4);
    short8 o;
    o[0] = (short)f2bf(w0.x); o[1] = (short)f2bf(w0.y);
    o[2] = (short)f2bf(w0.z); o[3] = (short)f2bf(w0.w);
    o[4] = (short)f2bf(w1.x); o[5] = (short)f2bf(w1.y);
    o[6] = (short)f2bf(w1.z); o[7] = (short)f2bf(w1.w);
    *(short8*)(Wf + (size_t)gid * 8) = o;
  }
}

// ---- fused conv + h_new: h(f32) -> A-frags (regs) -> hQf store + GEMM -----
// 128 blocks x 4 waves x 16 rows. hnV stored with k-permutation
// perm(8*lg+e) = 4*lg + (e<4 ? e : e+12) to match swapped-QK P register order.
__global__ __launch_bounds__(256) void hnew_k(const float* __restrict__ h,
                                              const unsigned short* __restrict__ Wf,
                                              const float* __restrict__ bias,
                                              unsigned short* __restrict__ hQf,
                                              unsigned short* __restrict__ hnb,
                                              unsigned short* __restrict__ hnV) {
  const int tid = threadIdx.x, w = tid >> 6, l = tid & 63, lr = l & 15, lg = l >> 4;
  const int row0 = blockIdx.x * 64 + w * 16;
  const int j16 = row0 >> 4;

  short8 a[8];
#pragma unroll
  for (int kk = 0; kk < 8; ++kk) {  // convert own rows f32 -> bf16 frags
    const float* src = h + (size_t)(row0 + lr) * DD + kk * 32 + lg * 8;
    float4 v0 = *(const float4*)src, v1 = *(const float4*)(src + 4);
    short8 o;
    o[0] = (short)f2bf(v0.x); o[1] = (short)f2bf(v0.y);
    o[2] = (short)f2bf(v0.z); o[3] = (short)f2bf(v0.w);
    o[4] = (short)f2bf(v1.x); o[5] = (short)f2bf(v1.y);
    o[6] = (short)f2bf(v1.z); o[7] = (short)f2bf(v1.w);
    a[kk] = o;
    *(short8*)(hQf + ((size_t)(j16 * 8 + kk) * 64 + l) * 8) = o;  // K/Q frags
  }

  f32x4 acc[16];
#pragma unroll
  for (int nt = 0; nt < 16; ++nt) acc[nt] = (f32x4){0.f, 0.f, 0.f, 0.f};
#pragma unroll
  for (int kk = 0; kk < 8; ++kk)
#pragma unroll
    for (int nt = 0; nt < 16; ++nt) {
      short8 bf = *(const short8*)(Wf + ((size_t)(nt * 8 + kk) * 64 + l) * 8);
      acc[nt] = mfma16(a[kk], bf, acc[nt]);
    }
  const int rowbase = row0 + lg * 4;                // 4 rows, q contiguous
  const int eb = ((rowbase >> 4) & 1) * 4;          // permuted elem base
#pragma unroll
  for (int nt = 0; nt < 16; ++nt) {
    const int col = nt * 16 + lr;
    const float bv = bias[col];
    unsigned short r16[4];
#pragma unroll
    for (int q = 0; q < 4; ++q) r16[q] = f2bf(acc[nt][q] + bv);
#pragma unroll
    for (int q = 0; q < 4; ++q) hnb[(size_t)(rowbase + q) * DD + col] = r16[q];
    ushort4 o4 = {r16[0], r16[1], r16[2], r16[3]};
    *(ushort4*)(hnV + (((size_t)(rowbase >> 5) * 16 + nt) * 64 + lg * 16 + lr) * 8 +
                eb) = o4;
  }
}

// ---- flash attention partials: swapped QK^T, register-only P --------------
// Grid (S=16 chunks, 128 tiles of 64 rows): chunk%8 = XCD (L2-pinned K/V).
// 4 waves x 16 rows; dbuf LDS; 2x unrolled; 1 barrier/iter.
// S2 = mfma(Kfrag, Qfrag) -> lane (lg,lr) holds P[lr][nt*16+4lg+q]; PV A-frag
// pa[e] = (e<4) ? p[0][e] : p[1][e-4] matches hnV's permuted k-order.
__global__ __launch_bounds__(256, 2) void attn_k(
    const unsigned short* __restrict__ hQf, const unsigned short* __restrict__ hnV,
    const int* __restrict__ adj, const int* __restrict__ kptr,
    float* __restrict__ pl, unsigned short* __restrict__ pO, int T) {
  __shared__ __align__(16) unsigned short sK[2][8192];   // 16KB x2
  __shared__ __align__(16) unsigned short sV[2][8192];   // 16KB x2

  const int tid = threadIdx.x, w = tid >> 6, l = tid & 63, lr = l & 15, lg = l >> 4;
  const int c = blockIdx.x, ty = blockIdx.y;
  const int i0 = ty * 64;
  const int kid = *kptr;
  if (i0 + 64 <= kid) return;  // whole tile identity: comb_k handles it

  const int r0 = i0 + w * 16;  // this wave's 16 rows

  short8 qf[8];  // Q frags (used as B operand; same lane layout as A)
#pragma unroll
  for (int kk = 0; kk < 8; ++kk)
    qf[kk] = *(const short8*)(hQf + ((size_t)((r0 >> 4) * 8 + kk) * 64 + l) * 8);

  f32x4 Oacc[16];
#pragma unroll
  for (int nt = 0; nt < 16; ++nt) Oacc[nt] = (f32x4){0.f, 0.f, 0.f, 0.f};
  float lsum = 0.f;                       // all 8 p/iter belong to row lr
  const float c1 = 0.09016844005556021f;  // log2(e)/sqrt(256)

  const size_t arow = (size_t)(r0 + lr) * NN;  // this lane's mask row

  const int jt0 = c * T;

  // ---- prologue: stage tile jt0 into buf 0, masks into avA (int4 x2) ----
  {
    const unsigned short* srcK = hQf + (size_t)jt0 * 8192;
    const unsigned short* srcV = hnV + (size_t)jt0 * 8192;
#pragma unroll
    for (int s = 0; s < 4; ++s) {
      const int so = (w * 4 + s) * 512;
      gld16(srcK + so + l * 8, &sK[0][so]);
      gld16(srcV + so + l * 8, &sV[0][so]);
    }
  }
  int avA[8], avB[8];
  {
    int4 t0 = *(const int4*)(adj + arow + jt0 * 32 + lg * 4);
    int4 t1 = *(const int4*)(adj + arow + jt0 * 32 + 16 + lg * 4);
    avA[0] = t0.x; avA[1] = t0.y; avA[2] = t0.z; avA[3] = t0.w;
    avA[4] = t1.x; avA[5] = t1.y; avA[6] = t1.z; avA[7] = t1.w;
  }
  __syncthreads();

#define ATTN_ITER(T_IDX, CUR, MC, MN)                                          \
  {                                                                            \
    const int t_ = (T_IDX);                                                    \
    if (t_ + 1 < T) { /* stage next tile + next masks */                       \
      const int jn = jt0 + t_ + 1;                                             \
      const unsigned short* srcK = hQf + (size_t)jn * 8192;                    \
      const unsigned short* srcV = hnV + (size_t)jn * 8192;                    \
      _Pragma("unroll") for (int s = 0; s < 4; ++s) {                          \
        const int so = (w * 4 + s) * 512;                                      \
        gld16(srcK + so + l * 8, &sK[(CUR) ^ 1][so]);                          \
        gld16(srcV + so + l * 8, &sV[(CUR) ^ 1][so]);                          \
      }                                                                        \
      int4 t0 = *(const int4*)(adj + arow + jn * 32 + lg * 4);                 \
      int4 t1 = *(const int4*)(adj + arow + jn * 32 + 16 + lg * 4);            \
      MN[0] = t0.x; MN[1] = t0.y; MN[2] = t0.z; MN[3] = t0.w;                  \
      MN[4] = t1.x; MN[5] = t1.y; MN[6] = t1.z; MN[7] = t1.w;                  \
    }                                                                          \
    f32x4 S2[2];                                                               \
    S2[0] = (f32x4){0.f, 0.f, 0.f, 0.f};                                       \
    S2[1] = (f32x4){0.f, 0.f, 0.f, 0.f};                                       \
    __builtin_amdgcn_s_setprio(1);                                             \
    _Pragma("unroll") for (int kk = 0; kk < 8; ++kk)                           \
      _Pragma("unroll") for (int nt = 0; nt < 2; ++nt) {                       \
        short8 kf = *(const short8*)(&sK[(CUR)][(nt * 8 + kk) * 512 + l * 8]); \
        S2[nt] = mfma16(kf, qf[kk], S2[nt]); /* swapped: S^T */                \
      }                                                                        \
    __builtin_amdgcn_s_setprio(0);                                             \
    float p[2][4];                                                             \
    _Pragma("unroll") for (int nt = 0; nt < 2; ++nt)                           \
      _Pragma("unroll") for (int q = 0; q < 4; ++q) {                          \
        float sv = MC[nt * 4 + q] ? fminf(S2[nt][q] * c1, 60.f) : NEGB;        \
        p[nt][q] = __builtin_amdgcn_exp2f(sv);                                 \
      }                                                                        \
    lsum += ((p[0][0] + p[0][1]) + (p[0][2] + p[0][3])) +                      \
            ((p[1][0] + p[1][1]) + (p[1][2] + p[1][3]));                       \
    short8 pa;                                                                 \
    _Pragma("unroll") for (int e = 0; e < 4; ++e) {                            \
      pa[e] = (short)f2bf(p[0][e]);                                            \
      pa[e + 4] = (short)f2bf(p[1][e]);                                        \
    }                                                                          \
    __builtin_amdgcn_s_setprio(1);                                             \
    _Pragma("unroll") for (int cnt = 0; cnt < 16; ++cnt) {                     \
      short8 vf = *(const short8*)(&sV[(CUR)][cnt * 512 + l * 8]);             \
      Oacc[cnt] = mfma16(pa, vf, Oacc[cnt]);                                   \
    }                                                                          \
    __builtin_amdgcn_s_setprio(0);                                             \
    __syncthreads();                                                           \
  }

  for (int tt = 0; tt < T; tt += 2) {
    ATTN_ITER(tt, 0, avA, avB);      // compute buf0/avA, stage buf1/avB
    ATTN_ITER(tt + 1, 1, avB, avA);  // compute buf1/avB, stage buf0/avA
  }
#undef ATTN_ITER

  // ---- reduce denominators across lg (shfl 16,32), write partials ----
  lsum += __shfl_xor(lsum, 16);
  lsum += __shfl_xor(lsum, 32);
  if (lg == 0) pl[(size_t)c * NN + r0 + lr] = lsum;
#pragma unroll
  for (int cnt = 0; cnt < 16; ++cnt)
#pragma unroll
    for (int q = 0; q < 4; ++q) {
      int row = r0 + lg * 4 + q;
      pO[((size_t)c * NN + row) * DD + cnt * 16 + lr] = f2bf(Oacc[cnt][q]);
    }
}

// ---- combine chunks + epilogue: 4 rows/block, ushort4 lanes ---------------
__global__ __launch_bounds__(256) void comb_k(const float* __restrict__ pl,
                                              const unsigned short* __restrict__ pO,
                                              const unsigned short* __restrict__ hnb,
                                              const int* __restrict__ kptr,
                                              float* __restrict__ out, int S) {
  const int row = blockIdx.x * 4 + (threadIdx.x >> 6);
  const int col = (threadIdx.x & 63) * 4;
  const int kid = *kptr;
  ushort4 hv = *(const ushort4*)(hnb + (size_t)row * DD + col);
  float v0 = bf2f(hv.x), v1 = bf2f(hv.y), v2 = bf2f(hv.z), v3 = bf2f(hv.w);
  float4 r;
  if (row < kid) {
    r.x = v0; r.y = v1; r.z = v2; r.w = v3;
  } else {
    float L = 0.f, a0 = 0.f, a1 = 0.f, a2 = 0.f, a3 = 0.f;
    for (int cc = 0; cc < S; ++cc) {
      L += pl[(size_t)cc * NN + row];
      ushort4 ov = *(const ushort4*)(pO + ((size_t)cc * NN + row) * DD + col);
      a0 += bf2f(ov.x); a1 += bf2f(ov.y); a2 += bf2f(ov.z); a3 += bf2f(ov.w);
    }
    float inv = 0.5f / L;
    r.x = a0 * inv + 0.5f * v0; r.y = a1 * inv + 0.5f * v1;
    r.z = a2 * inv + 0.5f * v2; r.w = a3 * inv + 0.5f * v3;
  }
  r.x = fmaxf(r.x, 0.f); r.y = fmaxf(r.y, 0.f);
  r.z = fmaxf(r.z, 0.f); r.w = fmaxf(r.w, 0.f);
  *(float4*)(out + (size_t)row * DD + col) = r;
}

extern "C" void kernel_launch(void* const* d_in, const int* in_sizes, int n_in,
                              void* d_out, int out_size, void* d_ws, size_t ws_size,
                              hipStream_t stream) {
  const float* h = (const float*)d_in[0];
  const int* adj = (const int*)d_in[1];
  const float* W = (const float*)d_in[2];
  const float* b = (const float*)d_in[3];
  float* out = (float*)d_out;

  char* ws = (char*)d_ws;
  const size_t MB4 = (size_t)NN * DD * 2;  // 4 MiB
  int* kbuf = (int*)ws;
  unsigned short* hQf = (unsigned short*)(ws + 256);
  unsigned short* hnb = (unsigned short*)(ws + 256 + MB4);
  unsigned short* hnV = (unsigned short*)(ws + 256 + 2 * MB4);
  unsigned short* Wf = (unsigned short*)(ws + 256 + 3 * MB4);  // 128 KiB
  char* dyn = ws + 256 + 3 * MB4 + (256 << 10);

  size_t fixed = 256 + 3 * MB4 + (256 << 10);
  int S = 16;
  while (S > 1 && fixed + (size_t)S * NN * (DD * 2 + 4) > ws_size) S >>= 1;
  const int T = 256 / S;

  float* pl = (float*)dyn;
  unsigned short* pO = (unsigned short*)(pl + (size_t)S * NN);

  hipLaunchKernelGGL(prep_k, dim3(33), dim3(256), 0, stream, W, adj, Wf, kbuf);
  hipLaunchKernelGGL(hnew_k, dim3(NN / 64), dim3(256), 0, stream,
                     h, Wf, b, hQf, hnb, hnV);
  hipLaunchKernelGGL(attn_k, dim3(S, NN / 64), dim3(256), 0, stream,
                     hQf, hnV, adj, kbuf, pl, pO, T);
  hipLaunchKernelGGL(comb_k, dim3(NN / 4), dim3(256), 0, stream, pl, pO, hnb, kbuf, out, S);
}

// Round 18
// 106.057 us; speedup vs baseline: 1.5305x; 1.0373x over previous
//
#include <hip/hip_runtime.h>

// GAT layer fused, MI355X gfx950 — v17 = v10 resubmitted (best measured:
// 106.1 us). v8's proven attn (16 rows/wave, sP P-transpose, dbuf, 2x
// unroll, XCD-pinned chunks, setprio) + fused prep (conv|count|packW) +
// col-split hnew. Pipeline: memset -> prep_k -> hnew_k -> attn_k -> comb_k.

typedef __attribute__((ext_vector_type(8))) short short8;   // 8 x bf16 (4 VGPR)
typedef __attribute__((ext_vector_type(4))) float f32x4;    // MFMA C/D frag

#define NN 8192
#define DD 256
#define NEGB -1.2983e16f  // -9e15 * log2(e): NEG_BIG in base-2 softmax domain

__device__ __forceinline__ unsigned short f2bf(float f) {
  unsigned u = __builtin_bit_cast(unsigned, f);
  u += 0x7FFFu + ((u >> 16) & 1u);  // RNE
  return (unsigned short)(u >> 16);
}
__device__ __forceinline__ float bf2f(unsigned short s) {
  unsigned u = ((unsigned)s) << 16;
  return __builtin_bit_cast(float, u);
}
__device__ __forceinline__ f32x4 mfma16(short8 a, short8 b, f32x4 c) {
  return __builtin_amdgcn_mfma_f32_16x16x32_bf16(a, b, c, 0, 0, 0);
}
// async global->LDS, 16B per lane; lds ptr wave-uniform base
__device__ __forceinline__ void gld16(const unsigned short* g, unsigned short* l) {
  __builtin_amdgcn_global_load_lds(
      (const __attribute__((address_space(1))) void*)g,
      (__attribute__((address_space(3))) void*)l, 16, 0, 0);
}

// ---- fused prep: conv_h (blocks 0..2047) | count_k (2048..2079) | pack_wf --
__global__ __launch_bounds__(256) void prep_k(const float* __restrict__ h,
                                              const float* __restrict__ W,
                                              const int* __restrict__ adj,
                                              unsigned short* __restrict__ hQf,
                                              unsigned short* __restrict__ Wf,
                                              int* __restrict__ kout) {
  const int bx = blockIdx.x, tid = threadIdx.x;
  if (bx < 2048) {  // h (f32) -> hQf bf16 MFMA frags
    int gid = bx * 256 + tid;
    int i = gid >> 6, k4 = (gid & 63) * 4;
    float4 v = *(const float4*)(h + (size_t)i * DD + k4);
    size_t off = ((size_t)((i >> 4) * 8 + (k4 >> 5)) * 64 +
                  (((k4 >> 3) & 3) * 16 + (i & 15))) * 8 + (k4 & 7);
    ushort4 o;
    o.x = f2bf(v.x); o.y = f2bf(v.y); o.z = f2bf(v.z); o.w = f2bf(v.w);
    *(ushort4*)(hQf + off) = o;
  } else if (bx < 2080) {  // k = sum(adj[:,0] != 0)
    __shared__ int red[256];
    int gid = (bx - 2048) * 256 + tid;
    red[tid] = (adj[(size_t)gid * NN] != 0);
    __syncthreads();
    for (int off = 128; off; off >>= 1) {
      if (tid < off) red[tid] += red[tid + off];
      __syncthreads();
    }
    if (tid == 0) atomicAdd(kout, red[0]);
  } else {  // W -> bf16 B-frags
    int gid = (bx - 2080) * 256 + tid;
    int l = gid & 63, f = gid >> 6, n16 = f >> 3, kk = f & 7;
    int lr = l & 15, lg = l >> 4;
    const float* src = W + (size_t)(n16 * 16 + lr) * DD + kk * 32 + lg * 8;
    float4 w0 = *(const float4*)src, w1 = *(const float4*)(src + 4);
    short8 o;
    o[0] = (short)f2bf(w0.x); o[1] = (short)f2bf(w0.y);
    o[2] = (short)f2bf(w0.z); o[3] = (short)f2bf(w0.w);
    o[4] = (short)f2bf(w1.x); o[5] = (short)f2bf(w1.y);
    o[6] = (short)f2bf(w1.z); o[7] = (short)f2bf(w1.w);
    *(short8*)(Wf + (size_t)gid * 8) = o;
  }
}

// ---- h_new = h @ W^T + b -> hnb + hnV frags; 256 blocks (row x col-half) --
__global__ __launch_bounds__(256) void hnew_k(const unsigned short* __restrict__ hQf,
                                              const unsigned short* __restrict__ Wf,
                                              const float* __restrict__ bias,
                                              unsigned short* __restrict__ hnb,
                                              unsigned short* __restrict__ hnV) {
  const int tid = threadIdx.x, w = tid >> 6, l = tid & 63, lr = l & 15, lg = l >> 4;
  const int row0 = (blockIdx.x >> 1) * 64 + w * 16;
  const int nt0 = (blockIdx.x & 1) * 8;

  short8 a[8];
#pragma unroll
  for (int kk = 0; kk < 8; ++kk)
    a[kk] = *(const short8*)(hQf + ((size_t)((row0 >> 4) * 8 + kk) * 64 + l) * 8);

  f32x4 acc[8];
#pragma unroll
  for (int nt = 0; nt < 8; ++nt) acc[nt] = (f32x4){0.f, 0.f, 0.f, 0.f};

#pragma unroll
  for (int kk = 0; kk < 8; ++kk)
#pragma unroll
    for (int nt = 0; nt < 8; ++nt) {
      short8 bf = *(const short8*)(Wf + ((size_t)((nt0 + nt) * 8 + kk) * 64 + l) * 8);
      acc[nt] = mfma16(a[kk], bf, acc[nt]);
    }
  const int rowbase = row0 + lg * 4;  // q = 0..3 contiguous within 8-run
#pragma unroll
  for (int nt = 0; nt < 8; ++nt) {
    const int col = (nt0 + nt) * 16 + lr;
    const float bv = bias[col];
    unsigned short r16[4];
#pragma unroll
    for (int q = 0; q < 4; ++q) r16[q] = f2bf(acc[nt][q] + bv);
#pragma unroll
    for (int q = 0; q < 4; ++q) hnb[(size_t)(rowbase + q) * DD + col] = r16[q];
    ushort4 o4 = {r16[0], r16[1], r16[2], r16[3]};
    *(ushort4*)(hnV + ((size_t)((rowbase >> 5) * 16 + nt0 + nt) * 64 +
                       ((rowbase >> 3) & 3) * 16 + lr) * 8 + (rowbase & 7)) = o4;
  }
}

// ---- flash attention partials (v8 structure + setprio) --------------------
// Grid (S=16 chunks, 128 tiles): chunk = blockIdx.x so chunk%8 = XCD -> each
// XCD L2 caches its 2 chunks' K/V frags. 4 waves x 16 rows; dbuf LDS;
// manual 2x unroll (fixed buffers, alternating mask regs); 1 barrier/iter.
__global__ __launch_bounds__(256, 2) void attn_k(
    const unsigned short* __restrict__ hQf, const unsigned short* __restrict__ hnV,
    const int* __restrict__ adj, const int* __restrict__ kptr,
    float* __restrict__ pl, unsigned short* __restrict__ pO, int T) {
  __shared__ __align__(16) unsigned short sK[2][8192];   // 16KB x2
  __shared__ __align__(16) unsigned short sV[2][8192];   // 16KB x2
  __shared__ __align__(16) unsigned short sP[4][16][40]; // per-wave P transpose

  const int tid = threadIdx.x, w = tid >> 6, l = tid & 63, lr = l & 15, lg = l >> 4;
  const int c = blockIdx.x, ty = blockIdx.y;
  const int i0 = ty * 64;
  const int kid = *kptr;
  if (i0 + 64 <= kid) return;  // whole tile identity: comb_k handles it

  const int r0 = i0 + w * 16;  // this wave's 16 rows

  short8 qf[8];  // Q A-frags
#pragma unroll
  for (int kk = 0; kk < 8; ++kk)
    qf[kk] = *(const short8*)(hQf + ((size_t)((r0 >> 4) * 8 + kk) * 64 + l) * 8);

  f32x4 Oacc[16];
#pragma unroll
  for (int nt = 0; nt < 16; ++nt) Oacc[nt] = (f32x4){0.f, 0.f, 0.f, 0.f};
  float lsum[4] = {0.f, 0.f, 0.f, 0.f};   // per-lane partial denominators
  const float c1 = 0.09016844005556021f;  // log2(e)/sqrt(256)

  int arow[4];
#pragma unroll
  for (int q = 0; q < 4; ++q) arow[q] = (r0 + lg * 4 + q) * NN;

  const int jt0 = c * T;

  // ---- prologue: stage tile jt0 into buf 0, load its adj into avA ----
  {
    const unsigned short* srcK = hQf + (size_t)jt0 * 8192;
    const unsigned short* srcV = hnV + (size_t)jt0 * 8192;
#pragma unroll
    for (int s = 0; s < 4; ++s) {
      const int so = (w * 4 + s) * 512;
      gld16(srcK + so + l * 8, &sK[0][so]);
      gld16(srcV + so + l * 8, &sV[0][so]);
    }
  }
  int avA[8], avB[8];
#pragma unroll
  for (int nt = 0; nt < 2; ++nt)
#pragma unroll
    for (int q = 0; q < 4; ++q)
      avA[nt * 4 + q] = adj[(size_t)arow[q] + jt0 * 32 + nt * 16 + lr];
  __syncthreads();

#define ATTN_ITER(T_IDX, CUR, MC, MN)                                          \
  {                                                                            \
    const int t_ = (T_IDX);                                                    \
    if (t_ + 1 < T) { /* stage next tile into other buffer, masks into MN */   \
      const int jn = jt0 + t_ + 1;                                             \
      const unsigned short* srcK = hQf + (size_t)jn * 8192;                    \
      const unsigned short* srcV = hnV + (size_t)jn * 8192;                    \
      _Pragma("unroll") for (int s = 0; s < 4; ++s) {                          \
        const int so = (w * 4 + s) * 512;                                      \
        gld16(srcK + so + l * 8, &sK[(CUR) ^ 1][so]);                          \
        gld16(srcV + so + l * 8, &sV[(CUR) ^ 1][so]);                          \
      }                                                                        \
      _Pragma("unroll") for (int nt = 0; nt < 2; ++nt)                         \
        _Pragma("unroll") for (int q = 0; q < 4; ++q)                          \
          MN[nt * 4 + q] = adj[(size_t)arow[q] + jn * 32 + nt * 16 + lr];      \
    }                                                                          \
    f32x4 S2[2];                                                               \
    S2[0] = (f32x4){0.f, 0.f, 0.f, 0.f};                                       \
    S2[1] = (f32x4){0.f, 0.f, 0.f, 0.f};                                       \
    __builtin_amdgcn_s_setprio(1);                                             \
    _Pragma("unroll") for (int kk = 0; kk < 8; ++kk)                           \
      _Pragma("unroll") for (int nt = 0; nt < 2; ++nt) {                       \
        short8 bf = *(const short8*)(&sK[(CUR)][(nt * 8 + kk) * 512 + l * 8]); \
        S2[nt] = mfma16(qf[kk], bf, S2[nt]);                                   \
      }                                                                        \
    __builtin_amdgcn_s_setprio(0);                                             \
    float p0[4], p1[4];                                                        \
    _Pragma("unroll") for (int q = 0; q < 4; ++q) {                            \
      float sv0 = MC[q] ? fminf(S2[0][q] * c1, 60.f) : NEGB;                   \
      float sv1 = MC[4 + q] ? fminf(S2[1][q] * c1, 60.f) : NEGB;               \
      p0[q] = __builtin_amdgcn_exp2f(sv0);                                     \
      p1[q] = __builtin_amdgcn_exp2f(sv1);                                     \
      lsum[q] += p0[q] + p1[q];                                                \
    }                                                                          \
    _Pragma("unroll") for (int q = 0; q < 4; ++q) {                            \
      sP[w][lg * 4 + q][lr] = f2bf(p0[q]);                                     \
      sP[w][lg * 4 + q][16 + lr] = f2bf(p1[q]);                                \
    }                                                                          \
    short8 pa = *(const short8*)(&sP[w][lr][lg * 8]);                          \
    __builtin_amdgcn_s_setprio(1);                                             \
    _Pragma("unroll") for (int cnt = 0; cnt < 16; ++cnt) {                     \
      short8 vf = *(const short8*)(&sV[(CUR)][cnt * 512 + l * 8]);             \
      Oacc[cnt] = mfma16(pa, vf, Oacc[cnt]);                                   \
    }                                                                          \
    __builtin_amdgcn_s_setprio(0);                                             \
    __syncthreads();                                                           \
  }

  for (int tt = 0; tt < T; tt += 2) {
    ATTN_ITER(tt, 0, avA, avB);      // compute buf0/avA, stage buf1/avB
    ATTN_ITER(tt + 1, 1, avB, avA);  // compute buf1/avB, stage buf0/avA
  }
#undef ATTN_ITER

  // ---- reduce denominators over lr (within 16-lane group), write partials --
#pragma unroll
  for (int q = 0; q < 4; ++q) {
#pragma unroll
    for (int off = 1; off < 16; off <<= 1) lsum[q] += __shfl_xor(lsum[q], off);
    if (lr == 0) pl[(size_t)c * NN + r0 + lg * 4 + q] = lsum[q];
  }
#pragma unroll
  for (int cnt = 0; cnt < 16; ++cnt)
#pragma unroll
    for (int q = 0; q < 4; ++q) {
      int row = r0 + lg * 4 + q;
      pO[((size_t)c * NN + row) * DD + cnt * 16 + lr] = f2bf(Oacc[cnt][q]);
    }
}

// ---- combine chunks + epilogue: 4 rows/block, ushort4 lanes ---------------
__global__ __launch_bounds__(256) void comb_k(const float* __restrict__ pl,
                                              const unsigned short* __restrict__ pO,
                                              const unsigned short* __restrict__ hnb,
                                              const int* __restrict__ kptr,
                                              float* __restrict__ out, int S) {
  const int row = blockIdx.x * 4 + (threadIdx.x >> 6);
  const int col = (threadIdx.x & 63) * 4;
  const int kid = *kptr;
  ushort4 hv = *(const ushort4*)(hnb + (size_t)row * DD + col);
  float v0 = bf2f(hv.x), v1 = bf2f(hv.y), v2 = bf2f(hv.z), v3 = bf2f(hv.w);
  float4 r;
  if (row < kid) {
    r.x = v0; r.y = v1; r.z = v2; r.w = v3;
  } else {
    float L = 0.f, a0 = 0.f, a1 = 0.f, a2 = 0.f, a3 = 0.f;
    for (int cc = 0; cc < S; ++cc) {
      L += pl[(size_t)cc * NN + row];
      ushort4 ov = *(const ushort4*)(pO + ((size_t)cc * NN + row) * DD + col);
      a0 += bf2f(ov.x); a1 += bf2f(ov.y); a2 += bf2f(ov.z); a3 += bf2f(ov.w);
    }
    float inv = 0.5f / L;
    r.x = a0 * inv + 0.5f * v0; r.y = a1 * inv + 0.5f * v1;
    r.z = a2 * inv + 0.5f * v2; r.w = a3 * inv + 0.5f * v3;
  }
  r.x = fmaxf(r.x, 0.f); r.y = fmaxf(r.y, 0.f);
  r.z = fmaxf(r.z, 0.f); r.w = fmaxf(r.w, 0.f);
  *(float4*)(out + (size_t)row * DD + col) = r;
}

extern "C" void kernel_launch(void* const* d_in, const int* in_sizes, int n_in,
                              void* d_out, int out_size, void* d_ws, size_t ws_size,
                              hipStream_t stream) {
  const float* h = (const float*)d_in[0];
  const int* adj = (const int*)d_in[1];
  const float* W = (const float*)d_in[2];
  const float* b = (const float*)d_in[3];
  float* out = (float*)d_out;

  char* ws = (char*)d_ws;
  const size_t MB4 = (size_t)NN * DD * 2;  // 4 MiB
  int* kbuf = (int*)ws;
  unsigned short* hQf = (unsigned short*)(ws + 256);
  unsigned short* hnb = (unsigned short*)(ws + 256 + MB4);
  unsigned short* hnV = (unsigned short*)(ws + 256 + 2 * MB4);
  unsigned short* Wf = (unsigned short*)(ws + 256 + 3 * MB4);  // 128 KiB
  char* dyn = ws + 256 + 3 * MB4 + (256 << 10);

  size_t fixed = 256 + 3 * MB4 + (256 << 10);
  int S = 16;
  while (S > 1 && fixed + (size_t)S * NN * (DD * 2 + 4) > ws_size) S >>= 1;
  const int T = 256 / S;

  float* pl = (float*)dyn;
  unsigned short* pO = (unsigned short*)(pl + (size_t)S * NN);

  hipMemsetAsync(kbuf, 0, 4, stream);
  hipLaunchKernelGGL(prep_k, dim3(2112), dim3(256), 0, stream, h, W, adj, hQf, Wf, kbuf);
  hipLaunchKernelGGL(hnew_k, dim3(256), dim3(256), 0, stream, hQf, Wf, b, hnb, hnV);
  hipLaunchKernelGGL(attn_k, dim3(S, NN / 64), dim3(256), 0, stream,
                     hQf, hnV, adj, kbuf, pl, pO, T);
  hipLaunchKernelGGL(comb_k, dim3(NN / 4), dim3(256), 0, stream, pl, pO, hnb, kbuf, out, S);
}